// Round 19
// baseline (1435.976 us; speedup 1.0000x reference)
//
#include <hip/hip_runtime.h>
#include <hip/hip_bf16.h>
#include <stdint.h>

#define DEV __device__ __forceinline__

typedef __bf16 bf16x8 __attribute__((ext_vector_type(8)));
typedef float f32x4 __attribute__((ext_vector_type(4)));
typedef unsigned short u16x8 __attribute__((ext_vector_type(8)));

constexpr int kB = 4, kT = 4096, kC = 2048, kH = 32, kN = 64;
constexpr int kM = kB * kT; // 16384
constexpr int SEGN = 8, TSEG = kT / SEGN, CHN = TSEG / 64; // 8 segments x 512 t x 8 chunks

// ---------- bf16 helpers ----------
DEV float bfu2f(unsigned short u) {
  union { uint32_t i; float f; } x; x.i = ((uint32_t)u) << 16; return x.f;
}
DEV unsigned short f2bfu(float f) {
  union { float f; uint32_t i; } x; x.f = f;
  uint32_t r = x.i + 0x7FFFu + ((x.i >> 16) & 1u);
  return (unsigned short)(r >> 16);
}

DEV void gld16(const void* g, void* l) {
  __builtin_amdgcn_global_load_lds(
      (const __attribute__((address_space(1))) void*)g,
      (__attribute__((address_space(3))) void*)l, 16, 0, 0);
}

// swizzled byte offset within a [rows][128B] LDS tile (row-major, 64 bf16/row)
DEV int swzb(int row, int byteoff) { return (row << 7) + (byteoff ^ ((row & 7) << 4)); }
// swizzled byte offset within a [rows][64B] K-slice LDS tile
DEV int swz64(int row, int byteoff) { return (row << 6) + (byteoff ^ ((row & 3) << 4)); }

// ---------- generic transpose + fp32->bf16 ----------
__global__ __launch_bounds__(256) void trans_bf16(
    const float* __restrict__ in, unsigned short* __restrict__ out, int R, int Cn) {
  __shared__ __attribute__((aligned(16))) unsigned short tile[64][65];
  const int t = threadIdx.x;
  const int r0 = blockIdx.y * 64, c0 = blockIdx.x * 64;
  const int lr = t >> 6, lc = t & 63;
#pragma unroll
  for (int i = 0; i < 16; i++) {
    int rr = lr + i * 4;
    int gr = r0 + rr, gc = c0 + lc;
    if (gr < R && gc < Cn) tile[rr][lc] = f2bfu(in[(size_t)gr * Cn + gc]);
  }
  __syncthreads();
#pragma unroll
  for (int i = 0; i < 16; i++) {
    int cc = lr + i * 4;
    int gc = c0 + cc, gr = r0 + lc;
    if (gc < Cn && gr < R) out[(size_t)gc * R + gr] = tile[lc][cc];
  }
}

// ---------- prep: xxx = bf16(x + (shift(x)-x)*maa_x), lx copy ----------
__global__ __launch_bounds__(256) void prep_x2(
    const float* __restrict__ x, const float* __restrict__ shift,
    const float* __restrict__ maax,
    unsigned short* __restrict__ xxx, float* __restrict__ lx) {
  size_t i4 = ((size_t)blockIdx.x * 256 + threadIdx.x) * 4;
  int c = (int)(i4 & (kC - 1));
  size_t bt = i4 >> 11;
  int tt = (int)(bt & (kT - 1));
  int b = (int)(bt >> 12);
  float4 xv = *(const float4*)(x + i4);
  float4 pv = (tt == 0) ? *(const float4*)(shift + (size_t)b * kC + c)
                        : *(const float4*)(x + i4 - kC);
  float4 mx = *(const float4*)(maax + c);
  ushort4 o4;
  o4.x = f2bfu(xv.x + (pv.x - xv.x) * mx.x);
  o4.y = f2bfu(xv.y + (pv.y - xv.y) * mx.y);
  o4.z = f2bfu(xv.z + (pv.z - xv.z) * mx.z);
  o4.w = f2bfu(xv.w + (pv.w - xv.w) * mx.w);
  *(ushort4*)(xxx + i4) = o4;
  if (tt == kT - 1) *(float4*)(lx + (size_t)b * kC + c) = xv;
}

enum { E_F32 = 0, E_BF16 = 1, E_TANH = 2, E_SILU = 3 };

// ---------- small-shape bf16 MFMA GEMM (m97-style 128-tile) ----------
template <int BM, int BN, int EPI>
__global__ __launch_bounds__(256) void gemm_k(
    const unsigned short* __restrict__ A, const unsigned short* __restrict__ Bt,
    void* __restrict__ Cout, int M, int N, int K) {
  constexpr int WGM = (BM == 128 && BN == 128) ? 2 : (BM == 64 ? 2 : 4);
  constexpr int WGN = 4 / WGM;
  constexpr int WM = BM / WGM, WN = BN / WGN;
  constexpr int WR = WM / 16, WC = WN / 16;
  __shared__ __attribute__((aligned(16))) unsigned short As[BM * 32];
  __shared__ __attribute__((aligned(16))) unsigned short Bs[BN * 32];
  const int t = threadIdx.x, wid = t >> 6, l = t & 63;
  const int m0 = blockIdx.x * BM, n0 = blockIdx.y * BN;
  const int wm0 = (wid / WGN) * WM, wn0 = (wid % WGN) * WN;
  f32x4 acc[WR][WC];
#pragma unroll
  for (int i = 0; i < WR; i++)
#pragma unroll
    for (int j = 0; j < WC; j++) acc[i][j] = f32x4{0.f, 0.f, 0.f, 0.f};

  const int rowS = t >> 2, cbS = (t & 3) * 16;
  const char* Ab = (const char*)A;
  const char* Bb = (const char*)Bt;
  const int aoff = (wm0 + (l & 15)) * 32 + (l >> 4) * 8;
  const int boff = (wn0 + (l & 15)) * 32 + (l >> 4) * 8;

  for (int kt = 0; kt < K; kt += 32) {
#pragma unroll
    for (int ia = 0; ia < BM / 64; ia++)
      gld16(Ab + ((size_t)(m0 + ia * 64 + rowS) * K + kt) * 2 + cbS,
            (char*)As + ia * 4096 + wid * 1024);
    if constexpr (BN >= 64) {
#pragma unroll
      for (int ib = 0; ib < BN / 64; ib++)
        gld16(Bb + ((size_t)(n0 + ib * 64 + rowS) * K + kt) * 2 + cbS,
              (char*)Bs + ib * 4096 + wid * 1024);
    } else {
      if (t < BN * 4)
        gld16(Bb + ((size_t)(n0 + rowS) * K + kt) * 2 + cbS,
              (char*)Bs + wid * 1024);
    }
    __syncthreads();
    bf16x8 af[WR], bfv[WC];
#pragma unroll
    for (int mi = 0; mi < WR; mi++) af[mi] = *(const bf16x8*)(&As[aoff + mi * 512]);
#pragma unroll
    for (int ni = 0; ni < WC; ni++) bfv[ni] = *(const bf16x8*)(&Bs[boff + ni * 512]);
#pragma unroll
    for (int mi = 0; mi < WR; mi++)
#pragma unroll
      for (int ni = 0; ni < WC; ni++)
        acc[mi][ni] = __builtin_amdgcn_mfma_f32_16x16x32_bf16(af[mi], bfv[ni], acc[mi][ni], 0, 0, 0);
    __syncthreads();
  }

#pragma unroll
  for (int mi = 0; mi < WR; mi++) {
#pragma unroll
    for (int ni = 0; ni < WC; ni++) {
      int row = m0 + wm0 + mi * 16 + (l >> 4) * 4;
      int col = n0 + wn0 + ni * 16 + (l & 15);
#pragma unroll
      for (int j = 0; j < 4; j++) {
        float v = acc[mi][ni][j];
        size_t idx = (size_t)(row + j) * N + col;
        if constexpr (EPI == E_F32) ((float*)Cout)[idx] = v;
        else if constexpr (EPI == E_BF16) ((unsigned short*)Cout)[idx] = f2bfu(v);
        else if constexpr (EPI == E_TANH) ((unsigned short*)Cout)[idx] = f2bfu(tanhf(v));
        else if constexpr (EPI == E_SILU) ((unsigned short*)Cout)[idx] = f2bfu(v / (1.f + expf(-v)));
      }
    }
  }
}

// ---------- big GEMM: 256x256 tile, BK=64, 8 waves, fine-phase schedule ----------
template <int EPI>
__global__ __launch_bounds__(512, 2) void gemm256_k(
    const unsigned short* __restrict__ A, const unsigned short* __restrict__ Bt,
    void* __restrict__ Cout, int M, int N, int K) {
  extern __shared__ __attribute__((aligned(16))) char lds[];
  const int tid = threadIdx.x, wid = tid >> 6, l = tid & 63;
  const int fr = l & 15, fq = l >> 4;

  const int mtiles = M >> 8, ntiles = N >> 8;
  const int slab = mtiles >> 3;
  const int xcd = blockIdx.x & 7, loc = blockIdx.x >> 3;
  const int m0 = (xcd * slab + loc / ntiles) * 256;
  const int n0 = (loc % ntiles) * 256;

  const int wm = (wid >> 2) * 128, wn = (wid & 3) * 64;

  const int srow0 = tid >> 2;
  const int scb = ((tid & 3) * 16) ^ ((srow0 & 3) << 4);
  const char* pa2[2]; const char* pb2[2];
#pragma unroll
  for (int i = 0; i < 2; i++) {
    pa2[i] = (const char*)A + (size_t)(m0 + i * 128 + srow0) * K * 2 + scb;
    pb2[i] = (const char*)Bt + (size_t)(n0 + i * 128 + srow0) * K * 2 + scb;
  }

  const char* vA[8]; const char* vB[4];
#pragma unroll
  for (int mi = 0; mi < 8; mi++)
    vA[mi] = lds + swz64(wm + mi * 16 + fr, fq * 16);
#pragma unroll
  for (int ni = 0; ni < 4; ni++)
    vB[ni] = lds + 32768 + swz64(wn + ni * 16 + fr, fq * 16);

  f32x4 acc[8][4];
#pragma unroll
  for (int i = 0; i < 8; i++)
#pragma unroll
    for (int j = 0; j < 4; j++) acc[i][j] = f32x4{0.f, 0.f, 0.f, 0.f};

  auto STG = [&](int q, int s, int ktb) {
    const int d = q * 65536 + s * 16384 + wid * 1024;
    gld16(pa2[0] + ktb + s * 64, lds + d);
    gld16(pa2[1] + ktb + s * 64, lds + d + 8192);
    gld16(pb2[0] + ktb + s * 64, lds + 32768 + d);
    gld16(pb2[1] + ktb + s * 64, lds + 32768 + d + 8192);
  };

  auto PH = [&](int p, int s, bool doStage, int ktbNext, int vm) {
    if (vm)
      asm volatile("s_waitcnt vmcnt(4)" ::: "memory");
    else
      asm volatile("s_waitcnt vmcnt(0)" ::: "memory");
    __builtin_amdgcn_s_barrier();
    __builtin_amdgcn_sched_barrier(0);
    const int pb = p * 65536 + s * 16384;
    bf16x8 a[8], b[4];
#pragma unroll
    for (int mi = 0; mi < 8; mi++) a[mi] = *(const bf16x8*)(vA[mi] + pb);
#pragma unroll
    for (int ni = 0; ni < 4; ni++) b[ni] = *(const bf16x8*)(vB[ni] + pb);
    if (doStage) STG(p ^ 1, s, ktbNext);
    __builtin_amdgcn_sched_barrier(0);
    __builtin_amdgcn_s_setprio(1);
#pragma unroll
    for (int ni = 0; ni < 4; ni++)
#pragma unroll
      for (int mi = 0; mi < 8; mi++)
        acc[mi][ni] = __builtin_amdgcn_mfma_f32_16x16x32_bf16(a[mi], b[ni], acc[mi][ni], 0, 0, 0);
    __builtin_amdgcn_s_setprio(0);
  };

  const int KT = K >> 6;
  STG(0, 0, 0);
  STG(0, 1, 0);

  int T = 0;
  for (; T + 2 < KT; T += 2) {
    PH(0, 0, true, (T + 1) * 128, 4);
    PH(0, 1, true, (T + 1) * 128, 4);
    PH(1, 0, true, (T + 2) * 128, 4);
    PH(1, 1, true, (T + 2) * 128, 4);
  }
  PH(0, 0, true, (KT - 1) * 128, 4);
  PH(0, 1, true, (KT - 1) * 128, 4);
  PH(1, 0, false, 0, 4);
  PH(1, 1, false, 0, 0);

#pragma unroll
  for (int mi = 0; mi < 8; mi++)
#pragma unroll
    for (int ni = 0; ni < 4; ni++) {
      int row = m0 + wm + mi * 16 + fq * 4;
      int col = n0 + wn + ni * 16 + fr;
#pragma unroll
      for (int j = 0; j < 4; j++) {
        float v = acc[mi][ni][j];
        size_t idx = (size_t)(row + j) * N + col;
        if constexpr (EPI == E_F32) ((float*)Cout)[idx] = v;
        else if constexpr (EPI == E_BF16) ((unsigned short*)Cout)[idx] = f2bfu(v);
        else if constexpr (EPI == E_SILU) ((unsigned short*)Cout)[idx] = f2bfu(v / (1.f + expf(-v)));
      }
    }
}

// ---------- five-feature mix: direct-global fragments, deferred nontemporal stores ----------
__global__ __launch_bounds__(256) void mix5f_k(
    const unsigned short* __restrict__ t5, const unsigned short* __restrict__ w2t,
    const float* __restrict__ x, const float* __restrict__ shift,
    const float* __restrict__ maaw, const float* __restrict__ maak,
    const float* __restrict__ maav, const float* __restrict__ maar,
    const float* __restrict__ maag,
    unsigned short* __restrict__ xw, unsigned short* __restrict__ xk,
    unsigned short* __restrict__ xvo, unsigned short* __restrict__ xr,
    unsigned short* __restrict__ xg) {
  __shared__ __attribute__((aligned(16))) float tile[64][68];   // 17408B
  const int t = threadIdx.x, wid = t >> 6, l = t & 63;
  const int m0 = blockIdx.x * 64, n0 = blockIdx.y * 64;
  const int wm0 = (wid >> 1) * 32, wn0 = (wid & 1) * 32;
  const int fr = l & 15, fq = l >> 4;

  // direct-global fragment base pointers (16B-aligned, 16B contiguous per lane)
  const unsigned short* pa0 = t5 + (size_t)(m0 + wm0 + fr) * 160 + fq * 8;
  const unsigned short* pa1 = t5 + (size_t)(m0 + wm0 + 16 + fr) * 160 + fq * 8;
  const unsigned short* pb0 = w2t + (size_t)(n0 + wn0 + fr) * 160 + fq * 8;
  const unsigned short* pb1 = w2t + (size_t)(n0 + wn0 + 16 + fr) * 160 + fq * 8;

  // row-contiguous epilogue operands: thread owns row (t>>2), 16 cols from (t&3)*16
  const int rrow = m0 + (t >> 2);
  const int c0 = (t & 3) * 16;
  const size_t base = (size_t)rrow * kC + n0 + c0;
  float xreg[16], dreg[16];
  {
    const int tt = rrow & (kT - 1);
    const float* pvp = (tt == 0) ? (shift + (size_t)(rrow >> 12) * kC + n0 + c0)
                                 : (x + base - kC);
#pragma unroll
    for (int q = 0; q < 4; q++) {
      float4 xv4 = *(const float4*)(x + base + q * 4);
      float4 pv4 = *(const float4*)(pvp + q * 4);
      xreg[q * 4 + 0] = xv4.x; dreg[q * 4 + 0] = pv4.x - xv4.x;
      xreg[q * 4 + 1] = xv4.y; dreg[q * 4 + 1] = pv4.y - xv4.y;
      xreg[q * 4 + 2] = xv4.z; dreg[q * 4 + 2] = pv4.z - xv4.z;
      xreg[q * 4 + 3] = xv4.w; dreg[q * 4 + 3] = pv4.w - xv4.w;
    }
  }

  // phase 1: per feature, MFMA + bounce + read m-values into registers (no stores)
  float mreg[80];
#pragma unroll
  for (int f = 0; f < 5; f++) {
    bf16x8 a0 = *(const bf16x8*)(pa0 + f * 32);
    bf16x8 a1 = *(const bf16x8*)(pa1 + f * 32);
    bf16x8 b0 = *(const bf16x8*)(pb0 + f * 32);
    bf16x8 b1 = *(const bf16x8*)(pb1 + f * 32);
    f32x4 ac00 = __builtin_amdgcn_mfma_f32_16x16x32_bf16(a0, b0, f32x4{0.f, 0.f, 0.f, 0.f}, 0, 0, 0);
    f32x4 ac01 = __builtin_amdgcn_mfma_f32_16x16x32_bf16(a0, b1, f32x4{0.f, 0.f, 0.f, 0.f}, 0, 0, 0);
    f32x4 ac10 = __builtin_amdgcn_mfma_f32_16x16x32_bf16(a1, b0, f32x4{0.f, 0.f, 0.f, 0.f}, 0, 0, 0);
    f32x4 ac11 = __builtin_amdgcn_mfma_f32_16x16x32_bf16(a1, b1, f32x4{0.f, 0.f, 0.f, 0.f}, 0, 0, 0);
    __syncthreads();   // prev feature's tile reads done (WAR)
#pragma unroll
    for (int j = 0; j < 4; j++) {
      tile[wm0 + fq * 4 + j][wn0 + fr]            = ac00[j];
      tile[wm0 + fq * 4 + j][wn0 + 16 + fr]       = ac01[j];
      tile[wm0 + 16 + fq * 4 + j][wn0 + fr]       = ac10[j];
      tile[wm0 + 16 + fq * 4 + j][wn0 + 16 + fr]  = ac11[j];
    }
    __syncthreads();   // tile ready
#pragma unroll
    for (int q = 0; q < 4; q++) {
      f32x4 m4 = *(const f32x4*)&tile[t >> 2][c0 + q * 4];
#pragma unroll
      for (int e = 0; e < 4; e++) mreg[f * 16 + q * 4 + e] = m4[e];
    }
  }

  // phase 2: all stores issued back-to-back, no barriers (drain at kernel end)
  unsigned short* outs[5] = { xw, xk, xvo, xr, xg };
  const float* maas[5] = { maaw, maak, maav, maar, maag };
#pragma unroll
  for (int f = 0; f < 5; f++) {
    const float* mp = maas[f] + n0 + c0;
    u16x8 o0, o1;
#pragma unroll
    for (int q = 0; q < 4; q++) {
      float4 ma4 = *(const float4*)(mp + q * 4);
      float mv[4] = { ma4.x, ma4.y, ma4.z, ma4.w };
#pragma unroll
      for (int e = 0; e < 4; e++) {
        int i = q * 4 + e;
        unsigned short r = f2bfu(xreg[i] + dreg[i] * (mv[e] + mreg[f * 16 + i]));
        if (i < 8) o0[i] = r; else o1[i - 8] = r;
      }
    }
    __builtin_nontemporal_store(o0, (u16x8*)(outs[f] + base));
    __builtin_nontemporal_store(o1, (u16x8*)(outs[f] + base + 8));
  }
}

// ---------- WKV pass 1: fused decay compute + local state (no edec materialization) ----------
__global__ __launch_bounds__(256) void wkv_local_k(
    const unsigned short* __restrict__ kb, const unsigned short* __restrict__ vb,
    const unsigned short* __restrict__ dtmp, const unsigned short* __restrict__ td2t,
    const float* __restrict__ tdec,
    float* __restrict__ Lbuf, float* __restrict__ Dseg) {
  const int bid = blockIdx.x;
  const int bh = bid >> 3, seg = bid & 7;
  const int h = bh & 31, b = bh >> 5;
  const int tid = threadIdx.x, w = tid >> 6, l = tid & 63;
  __shared__ __attribute__((aligned(16))) char arena[32768];
  char* KQks = arena;
  char* Vt   = arena + 8192;
  float* EdB = (float*)arena;        // aliases KQks+Vt (16KB) early in chunk
  char* TdB  = arena + 16384;        // persistent
  char* DtA  = arena + 24576;        // per-chunk
  __shared__ float segp[4][64];
  __shared__ float DLs[64];
  __shared__ float tdf[64];

  const int fr = l & 15, fq = l >> 4;
  f32x4 Sreg[4];
#pragma unroll
  for (int ni = 0; ni < 4; ni++) Sreg[ni] = f32x4{0.f, 0.f, 0.f, 0.f};

  {
    int r1 = tid >> 3, r2 = 32 + r1;
    int cb1 = ((tid & 7) * 16) ^ ((r1 & 7) << 4);
    int cb2 = ((tid & 7) * 16) ^ ((r2 & 7) << 4);
    gld16((const char*)td2t + (size_t)(h * 64 + r1) * 128 + cb1, TdB + w * 1024);
    gld16((const char*)td2t + (size_t)(h * 64 + r2) * 128 + cb2, TdB + 4096 + w * 1024);
    if (tid < 64) tdf[tid] = tdec[h * 64 + tid];
  }

  float dtot = 1.f;
  float kv[16], vv[16];
  {
    size_t g = ((size_t)b * kT + seg * TSEG + w * 16) * kC + h * 64 + l;
#pragma unroll
    for (int i = 0; i < 16; i++) {
      kv[i] = bfu2f(kb[g]); vv[i] = bfu2f(vb[g]);
      g += kC;
    }
  }

  for (int ch = 0; ch < CHN; ++ch) {
    const size_t gt0 = (size_t)b * kT + seg * TSEG + ch * 64;
    {
      int r1 = tid >> 3, r2 = 32 + r1;
      int cb1 = ((tid & 7) * 16) ^ ((r1 & 7) << 4);
      int cb2 = ((tid & 7) * 16) ^ ((r2 & 7) << 4);
      gld16((const char*)dtmp + (gt0 + r1) * 128 + cb1, DtA + w * 1024);
      gld16((const char*)dtmp + (gt0 + r2) * 128 + cb2, DtA + 4096 + w * 1024);
    }
    __syncthreads();  // B0: DtA staged; prev-chunk KQks/Vt reads complete

    f32x4 dacc[4];
    {
      bf16x8 af0 = *(const bf16x8*)(DtA + swzb(w * 16 + fr, fq * 16));
      bf16x8 af1 = *(const bf16x8*)(DtA + swzb(w * 16 + fr, fq * 16 + 64));
#pragma unroll
      for (int nj = 0; nj < 4; nj++) {
        bf16x8 b0 = *(const bf16x8*)(TdB + swzb(nj * 16 + fr, fq * 16));
        bf16x8 b1 = *(const bf16x8*)(TdB + swzb(nj * 16 + fr, fq * 16 + 64));
        dacc[nj] = __builtin_amdgcn_mfma_f32_16x16x32_bf16(af0, b0, f32x4{0.f, 0.f, 0.f, 0.f}, 0, 0, 0);
        dacc[nj] = __builtin_amdgcn_mfma_f32_16x16x32_bf16(af1, b1, dacc[nj], 0, 0, 0);
      }
    }
    // EdB write/read is wave-local (rows w*16..w*16+15) — no barrier needed
#pragma unroll
    for (int nj = 0; nj < 4; nj++) {
      float tv = tdf[nj * 16 + fr];
#pragma unroll
      for (int j = 0; j < 4; j++)
        EdB[(w * 16 + fq * 4 + j) * 64 + nj * 16 + fr] = expf(-expf(dacc[nj][j] + tv));
    }
    float dvv[16];
    float p = 1.f;
#pragma unroll
    for (int i = 0; i < 16; i++) {
      float d = EdB[(w * 16 + i) * 64 + l];
      dvv[i] = d; p *= d;
    }
    segp[w][l] = p;
    __syncthreads();  // B2: segp ready; all EdB reads done (KQks/Vt may be overwritten)

    float pre = 1.f;
    if (w > 0) pre *= segp[0][l];
    if (w > 1) pre *= segp[1][l];
    if (w > 2) pre *= segp[2][l];
    if (w == 3) DLs[l] = pre * p;

    unsigned short kqrow[16], vtrow[16];
    float run = pre;
#pragma unroll
    for (int i = 0; i < 16; i++) {
      run *= dvv[i];
      kqrow[i] = f2bfu(kv[i] / run);
      vtrow[i] = f2bfu(vv[i]);
    }
    {
      u16x8 q0, q1, v0, v1;
#pragma unroll
      for (int j = 0; j < 8; j++) { q0[j] = kqrow[j]; q1[j] = kqrow[j + 8]; v0[j] = vtrow[j]; v1[j] = vtrow[j + 8]; }
      *(u16x8*)(KQks + swzb(l, w * 32)) = q0;
      *(u16x8*)(KQks + swzb(l, w * 32 + 16)) = q1;
      *(u16x8*)(Vt + swzb(l, w * 32)) = v0;
      *(u16x8*)(Vt + swzb(l, w * 32 + 16)) = v1;
    }
    if (ch < CHN - 1) {
      size_t g = ((size_t)b * kT + seg * TSEG + (ch + 1) * 64 + w * 16) * kC + h * 64 + l;
#pragma unroll
      for (int i = 0; i < 16; i++) {
        kv[i] = bfu2f(kb[g]); vv[i] = bfu2f(vb[g]);
        g += kC;
      }
    }
    __syncthreads();  // B3: tiles ready

    bf16x8 kA0 = *(const bf16x8*)(KQks + swzb(w * 16 + fr, fq * 16));
    bf16x8 kA1 = *(const bf16x8*)(KQks + swzb(w * 16 + fr, fq * 16 + 64));
    f32x4 kvacc[4];
#pragma unroll
    for (int ni = 0; ni < 4; ni++) {
      bf16x8 bv0 = *(const bf16x8*)(Vt + swzb(ni * 16 + fr, fq * 16));
      bf16x8 bv1 = *(const bf16x8*)(Vt + swzb(ni * 16 + fr, fq * 16 + 64));
      kvacc[ni] = __builtin_amdgcn_mfma_f32_16x16x32_bf16(kA0, bv0, f32x4{0.f, 0.f, 0.f, 0.f}, 0, 0, 0);
      kvacc[ni] = __builtin_amdgcn_mfma_f32_16x16x32_bf16(kA1, bv1, kvacc[ni], 0, 0, 0);
    }
    float dlj[4];
#pragma unroll
    for (int j = 0; j < 4; j++) dlj[j] = DLs[w * 16 + fq * 4 + j];
#pragma unroll
    for (int ni = 0; ni < 4; ni++)
#pragma unroll
      for (int j = 0; j < 4; j++)
        Sreg[ni][j] = (Sreg[ni][j] + kvacc[ni][j]) * dlj[j];
    dtot *= DLs[l];
  }

  float* Lp = Lbuf + (size_t)bid * 4096;
#pragma unroll
  for (int ni = 0; ni < 4; ni++)
#pragma unroll
    for (int j = 0; j < 4; j++)
      Lp[(size_t)(w * 16 + fq * 4 + j) * 64 + ni * 16 + fr] = Sreg[ni][j];
  if (w == 0) Dseg[(size_t)bid * 64 + l] = dtot;
}

// ---------- WKV combine ----------
__global__ __launch_bounds__(256) void wkv_combine_k(
    const float* __restrict__ s0, const float* __restrict__ Dseg,
    float* __restrict__ Lbuf, float* __restrict__ sOut) {
  const int bh = blockIdx.x, tid = threadIdx.x;
  const int k = tid >> 2, v0 = (tid & 3) * 16;
  float4 s[4];
  const float* sp = s0 + (size_t)bh * 4096 + (size_t)k * 64 + v0;
#pragma unroll
  for (int q = 0; q < 4; q++) s[q] = ((const float4*)sp)[q];
  for (int seg = 0; seg < SEGN; ++seg) {
    size_t idx = (size_t)bh * SEGN + seg;
    float d = Dseg[idx * 64 + k];
    float* Lp = Lbuf + idx * 4096 + (size_t)k * 64 + v0;
#pragma unroll
    for (int q = 0; q < 4; q++) {
      float4 lq = ((float4*)Lp)[q];
      ((float4*)Lp)[q] = s[q];
      s[q].x = d * s[q].x + lq.x; s[q].y = d * s[q].y + lq.y;
      s[q].z = d * s[q].z + lq.z; s[q].w = d * s[q].w + lq.w;
    }
  }
  float* op = sOut + (size_t)bh * 4096 + (size_t)k * 64 + v0;
#pragma unroll
  for (int q = 0; q < 4; q++) ((float4*)op)[q] = s[q];
}

// ---------- WKV pass 2: fused decay recompute (no edec read), o -> HBM ----------
__global__ __launch_bounds__(256) void wkv_seg_k(
    const unsigned short* __restrict__ rb, const unsigned short* __restrict__ kb,
    const unsigned short* __restrict__ vb,
    const unsigned short* __restrict__ dtmp, const unsigned short* __restrict__ td2t,
    const float* __restrict__ tdec,
    const float* __restrict__ uf, const float* __restrict__ Sini,
    unsigned short* __restrict__ o) {
  const int bid = blockIdx.x;
  const int bh = bid >> 3, seg = bid & 7;
  const int h = bh & 31, b = bh >> 5;
  const int tid = threadIdx.x, w = tid >> 6, l = tid & 63;
  // arena layout (8KB each): RQ, KQsk, KQks, Vt, Pl, S0T, RU, Ksk
  // aliases: EdB f32 (16KB) over RQ+KQsk; DtA over RU; TdB over Ksk
  __shared__ __attribute__((aligned(16))) char arena[65536];
  char* RQ   = arena;
  char* KQsk = arena + 8192;
  char* KQks = arena + 16384;
  char* Vt   = arena + 24576;
  char* Pl   = arena + 32768;
  char* S0T  = arena + 40960;
  char* RU   = arena + 49152;
  char* Ksk  = arena + 57344;
  float* EdB = (float*)arena;
  char* DtA  = RU;
  char* TdB  = Ksk;
  __shared__ float segp[4][64];
  __shared__ float DLs[64];
  __shared__ float tdf[64];

  const float uu = uf[h * 64 + l];
  const int fr = l & 15, fq = l >> 4;
  if (tid < 64) tdf[tid] = tdec[h * 64 + tid];

  f32x4 Sreg[4];
#pragma unroll
  for (int ni = 0; ni < 4; ni++)
#pragma unroll
    for (int j = 0; j < 4; j++) {
      int kk2 = w * 16 + fq * 4 + j, vv2 = ni * 16 + fr;
      float sv = Sini[(size_t)bid * 4096 + (size_t)kk2 * 64 + vv2];
      Sreg[ni][j] = sv;
      *(unsigned short*)(S0T + swzb(vv2, kk2 * 2)) = f2bfu(sv);
    }
  __syncthreads();

  float rv[16], kv[16], vv[16];
  {
    size_t g = ((size_t)b * kT + seg * TSEG + w * 16) * kC + h * 64 + l;
#pragma unroll
    for (int i = 0; i < 16; i++) {
      rv[i] = bfu2f(rb[g]); kv[i] = bfu2f(kb[g]); vv[i] = bfu2f(vb[g]);
      g += kC;
    }
  }

  const int r1s = tid >> 3, r2s = 32 + r1s;
  const int cb1 = ((tid & 7) * 16) ^ ((r1s & 7) << 4);
  const int cb2 = ((tid & 7) * 16) ^ ((r2s & 7) << 4);

  for (int ch = 0; ch < CHN; ++ch) {
    const size_t gt0 = (size_t)b * kT + seg * TSEG + ch * 64;
    // stage DtA (dtmp tile) + TdB (td2t tile) into RU/Ksk slots
    gld16((const char*)dtmp + (gt0 + r1s) * 128 + cb1, DtA + w * 1024);
    gld16((const char*)dtmp + (gt0 + r2s) * 128 + cb2, DtA + 4096 + w * 1024);
    gld16((const char*)td2t + (size_t)(h * 64 + r1s) * 128 + cb1, TdB + w * 1024);
    gld16((const char*)td2t + (size_t)(h * 64 + r2s) * 128 + cb2, TdB + 4096 + w * 1024);
    __syncthreads();   // S1: stage drained; prev-chunk reads of aliased slots done

    // decay GEMM -> EdB (f32, aliases RQ+KQsk); write/read wave-local
    f32x4 dacc[4];
    {
      bf16x8 af0 = *(const bf16x8*)(DtA + swzb(w * 16 + fr, fq * 16));
      bf16x8 af1 = *(const bf16x8*)(DtA + swzb(w * 16 + fr, fq * 16 + 64));
#pragma unroll
      for (int nj = 0; nj < 4; nj++) {
        bf16x8 b0 = *(const bf16x8*)(TdB + swzb(nj * 16 + fr, fq * 16));
        bf16x8 b1 = *(const bf16x8*)(TdB + swzb(nj * 16 + fr, fq * 16 + 64));
        dacc[nj] = __builtin_amdgcn_mfma_f32_16x16x32_bf16(af0, b0, f32x4{0.f, 0.f, 0.f, 0.f}, 0, 0, 0);
        dacc[nj] = __builtin_amdgcn_mfma_f32_16x16x32_bf16(af1, b1, dacc[nj], 0, 0, 0);
      }
    }
#pragma unroll
    for (int nj = 0; nj < 4; nj++) {
      float tv = tdf[nj * 16 + fr];
#pragma unroll
      for (int j = 0; j < 4; j++)
        EdB[(w * 16 + fq * 4 + j) * 64 + nj * 16 + fr] = expf(-expf(dacc[nj][j] + tv));
    }
    float dv[16];
    float p = 1.f;
#pragma unroll
    for (int i = 0; i < 16; i++) {
      dv[i] = EdB[(w * 16 + i) * 64 + l];
      p *= dv[i];
    }
    segp[w][l] = p;
    __syncthreads();   // S2: segp ready; EdB reads done; decay MFMA reads of DtA/TdB done

    float pre = 1.f;
    if (w > 0) pre *= segp[0][l];
    if (w > 1) pre *= segp[1][l];
    if (w > 2) pre *= segp[2][l];
    if (w == 3) DLs[l] = pre * p;

    unsigned short kqrow[16], vtrow[16];
    float run = pre;
#pragma unroll
    for (int i = 0; i < 16; i++) {
      int t = w * 16 + i;
      float rq = rv[i] * run;
      run *= dv[i];
      float kq = kv[i] / run;
      *(unsigned short*)(RQ + swzb(t, l * 2)) = f2bfu(rq);
      *(unsigned short*)(RU + swzb(t, l * 2)) = f2bfu(rv[i] * uu);
      *(unsigned short*)(Ksk + swzb(t, l * 2)) = f2bfu(kv[i]);
      unsigned short kqu = f2bfu(kq);
      *(unsigned short*)(KQsk + swzb(t, l * 2)) = kqu;
      kqrow[i] = kqu;
      vtrow[i] = f2bfu(vv[i]);
    }
    {
      u16x8 q0, q1, v0, v1;
#pragma unroll
      for (int j = 0; j < 8; j++) { q0[j] = kqrow[j]; q1[j] = kqrow[j + 8]; v0[j] = vtrow[j]; v1[j] = vtrow[j + 8]; }
      *(u16x8*)(KQks + swzb(l, w * 32)) = q0;
      *(u16x8*)(KQks + swzb(l, w * 32 + 16)) = q1;
      *(u16x8*)(Vt + swzb(l, w * 32)) = v0;
      *(u16x8*)(Vt + swzb(l, w * 32 + 16)) = v1;
    }

    if (ch < CHN - 1) {
      size_t g = ((size_t)b * kT + seg * TSEG + (ch + 1) * 64 + w * 16) * kC + h * 64 + l;
#pragma unroll
      for (int i = 0; i < 16; i++) {
        rv[i] = bfu2f(rb[g]); kv[i] = bfu2f(kb[g]); vv[i] = bfu2f(vb[g]);
        g += kC;
      }
    }
    __syncthreads();   // S3: tiles ready

    bf16x8 a0 = *(const bf16x8*)(RQ + swzb(w * 16 + fr, fq * 16));
    bf16x8 a1 = *(const bf16x8*)(RQ + swzb(w * 16 + fr, fq * 16 + 64));
    f32x4 pacc[4];
#pragma unroll
    for (int ni = 0; ni < 4; ni++) {
      bf16x8 b0 = *(const bf16x8*)(KQsk + swzb(ni * 16 + fr, fq * 16));
      bf16x8 b1 = *(const bf16x8*)(KQsk + swzb(ni * 16 + fr, fq * 16 + 64));
      pacc[ni] = __builtin_amdgcn_mfma_f32_16x16x32_bf16(a0, b0, f32x4{0.f, 0.f, 0.f, 0.f}, 0, 0, 0);
      pacc[ni] = __builtin_amdgcn_mfma_f32_16x16x32_bf16(a1, b1, pacc[ni], 0, 0, 0);
    }
    f32x4 dacc2;
    {
      bf16x8 ru0 = *(const bf16x8*)(RU + swzb(w * 16 + fr, fq * 16));
      bf16x8 ru1 = *(const bf16x8*)(RU + swzb(w * 16 + fr, fq * 16 + 64));
      bf16x8 kb0 = *(const bf16x8*)(Ksk + swzb(w * 16 + fr, fq * 16));
      bf16x8 kb1 = *(const bf16x8*)(Ksk + swzb(w * 16 + fr, fq * 16 + 64));
      dacc2 = __builtin_amdgcn_mfma_f32_16x16x32_bf16(ru0, kb0, f32x4{0.f, 0.f, 0.f, 0.f}, 0, 0, 0);
      dacc2 = __builtin_amdgcn_mfma_f32_16x16x32_bf16(ru1, kb1, dacc2, 0, 0, 0);
    }
    float dg[4];
#pragma unroll
    for (int j = 0; j < 4; j++) dg[j] = __shfl(dacc2[j], fq * 20 + j, 64);
#pragma unroll
    for (int ni = 0; ni < 4; ni++)
#pragma unroll
      for (int j = 0; j < 4; j++) {
        int row = w * 16 + fq * 4 + j, col = ni * 16 + fr;
        float pv = pacc[ni][j];
        pv = (col < row) ? pv : ((col == row) ? dg[j] : 0.f);
        *(unsigned short*)(Pl + swzb(row, col * 2)) = f2bfu(pv);
      }
    __syncthreads();   // S4

    bf16x8 pA0 = *(const bf16x8*)(Pl + swzb(w * 16 + fr, fq * 16));
    bf16x8 pA1 = *(const bf16x8*)(Pl + swzb(w * 16 + fr, fq * 16 + 64));
    bf16x8 kA0 = *(const bf16x8*)(KQks + swzb(w * 16 + fr, fq * 16));
    bf16x8 kA1 = *(const bf16x8*)(KQks + swzb(w * 16 + fr, fq * 16 + 64));
    f32x4 oacc[4], kvacc[4];
#pragma unroll
    for (int ni = 0; ni < 4; ni++) {
      bf16x8 bv0 = *(const bf16x8*)(Vt + swzb(ni * 16 + fr, fq * 16));
      bf16x8 bv1 = *(const bf16x8*)(Vt + swzb(ni * 16 + fr, fq * 16 + 64));
      bf16x8 bs0 = *(const bf16x8*)(S0T + swzb(ni * 16 + fr, fq * 16));
      bf16x8 bs1 = *(const bf16x8*)(S0T + swzb(ni * 16 + fr, fq * 16 + 64));
      oacc[ni] = __builtin_amdgcn_mfma_f32_16x16x32_bf16(pA0, bv0, f32x4{0.f, 0.f, 0.f, 0.f}, 0, 0, 0);
      oacc[ni] = __builtin_amdgcn_mfma_f32_16x16x32_bf16(pA1, bv1, oacc[ni], 0, 0, 0);
      oacc[ni] = __builtin_amdgcn_mfma_f32_16x16x32_bf16(a0, bs0, oacc[ni], 0, 0, 0);
      oacc[ni] = __builtin_amdgcn_mfma_f32_16x16x32_bf16(a1, bs1, oacc[ni], 0, 0, 0);
      kvacc[ni] = __builtin_amdgcn_mfma_f32_16x16x32_bf16(kA0, bv0, f32x4{0.f, 0.f, 0.f, 0.f}, 0, 0, 0);
      kvacc[ni] = __builtin_amdgcn_mfma_f32_16x16x32_bf16(kA1, bv1, kvacc[ni], 0, 0, 0);
    }
    size_t obase = gt0 * kC + h * 64;
#pragma unroll
    for (int ni = 0; ni < 4; ni++)
#pragma unroll
      for (int j = 0; j < 4; j++)
        o[obase + (size_t)(w * 16 + fq * 4 + j) * kC + ni * 16 + fr] = f2bfu(oacc[ni][j]);
    __syncthreads();   // S5

    float dlj[4];
#pragma unroll
    for (int j = 0; j < 4; j++) dlj[j] = DLs[w * 16 + fq * 4 + j];
#pragma unroll
    for (int ni = 0; ni < 4; ni++)
#pragma unroll
      for (int j = 0; j < 4; j++) {
        int kk2 = w * 16 + fq * 4 + j, vv2 = ni * 16 + fr;
        float sn = (Sreg[ni][j] + kvacc[ni][j]) * dlj[j];
        Sreg[ni][j] = sn;
        *(unsigned short*)(S0T + swzb(vv2, kk2 * 2)) = f2bfu(sn);
      }
    // no end barrier: next chunk's S1 orders all remaining hazards
  }
}

// ---------- GroupNorm over N=64 per (b,t,h), times g, -> bf16 ----------
__global__ __launch_bounds__(256) void gn_k(
    const unsigned short* __restrict__ o, const unsigned short* __restrict__ gb,
    const float* __restrict__ gnw, const float* __restrict__ gnb,
    unsigned short* __restrict__ y) {
  int gi = blockIdx.x * 4 + (threadIdx.x >> 6);
  int j = threadIdx.x & 63;
  int bt = gi >> 5, h = gi & 31;
  size_t idx = (size_t)bt * kC + h * 64 + j;
  float val = bfu2f(o[idx]);
  float s = val, s2 = val * val;
#pragma unroll
  for (int m = 1; m < 64; m <<= 1) {
    s += __shfl_xor(s, m, 64);
    s2 += __shfl_xor(s2, m, 64);
  }
  float mu = s * 0.015625f;
  float var = s2 * 0.015625f - mu * mu;
  float rs = rsqrtf(var + 6.4e-4f);
  float on = (val - mu) * rs * gnw[h * 64 + j] + gnb[h * 64 + j];
  y[idx] = f2bfu(on * bfu2f(gb[idx]));
}

// ---------- workspace layout ----------
constexpr size_t SZW     = (size_t)2048 * 2048 * 2;
constexpr size_t OFF_WRT = 0;
constexpr size_t OFF_WKT = 1 * SZW;
constexpr size_t OFF_WVT = 2 * SZW;
constexpr size_t OFF_WGT = 3 * SZW;
constexpr size_t OFF_WOT = 4 * SZW;
constexpr size_t OFF_W1T = 5 * SZW;
constexpr size_t OFF_W2T = OFF_W1T + (size_t)160 * 2048 * 2;
constexpr size_t OFF_TD1 = OFF_W2T + (size_t)2048 * 160 * 2;     // later Dseg f32
constexpr size_t OFF_TD2 = OFF_TD1 + (size_t)64 * 2048 * 2;
constexpr size_t OFF_T5  = OFF_TD2 + (size_t)2048 * 64 * 2;
constexpr size_t OFF_DT  = OFF_T5 + (size_t)kM * 160 * 2;
constexpr size_t OFF_XG  = OFF_DT + (size_t)kM * 64 * 2;         // xg bf16; later o bf16 + y bf16
constexpr size_t OFF_X   = OFF_XG + (size_t)kM * kC * 4;         // xxx/xw; k
constexpr size_t OFF_R   = OFF_X + (size_t)kM * kC * 2;          // xv; r
constexpr size_t OFF_K   = OFF_R + (size_t)kM * kC * 2;          // xr; g
constexpr size_t OFF_V   = OFF_K + (size_t)kM * kC * 2;          // xk; v
constexpr size_t OFF_L   = OFF_WRT;

extern "C" void kernel_launch(void* const* d_in, const int* in_sizes, int n_in,
                              void* d_out, int out_size, void* d_ws, size_t ws_size,
                              hipStream_t stream) {
  const float* x     = (const float*)d_in[0];
  const float* shift = (const float*)d_in[1];
  const float* s0    = (const float*)d_in[2];
  const float* maax  = (const float*)d_in[3];
  const float* maaw  = (const float*)d_in[4];
  const float* maak  = (const float*)d_in[5];
  const float* maav  = (const float*)d_in[6];
  const float* maar  = (const float*)d_in[7];
  const float* maag  = (const float*)d_in[8];
  const float* w1    = (const float*)d_in[9];
  const float* w2    = (const float*)d_in[10];
  const float* tdec  = (const float*)d_in[11];
  const float* tdw1  = (const float*)d_in[12];
  const float* tdw2  = (const float*)d_in[13];
  const float* faaaa = (const float*)d_in[14];
  const float* Wr    = (const float*)d_in[15];
  const float* Wk    = (const float*)d_in[16];
  const float* Wv    = (const float*)d_in[17];
  const float* Wg    = (const float*)d_in[18];
  const float* Wo    = (const float*)d_in[19];
  const float* gnw   = (const float*)d_in[20];
  const float* gnb   = (const float*)d_in[21];

  char* ws = (char*)d_ws;
  unsigned short* Wrt  = (unsigned short*)(ws + OFF_WRT);
  unsigned short* Wkt  = (unsigned short*)(ws + OFF_WKT);
  unsigned short* Wvt  = (unsigned short*)(ws + OFF_WVT);
  unsigned short* Wgt  = (unsigned short*)(ws + OFF_WGT);
  unsigned short* Wot  = (unsigned short*)(ws + OFF_WOT);
  unsigned short* w1t  = (unsigned short*)(ws + OFF_W1T);
  unsigned short* w2t  = (unsigned short*)(ws + OFF_W2T);
  unsigned short* td1t = (unsigned short*)(ws + OFF_TD1);
  unsigned short* td2t = (unsigned short*)(ws + OFF_TD2);
  unsigned short* t5   = (unsigned short*)(ws + OFF_T5);
  unsigned short* dtmp = (unsigned short*)(ws + OFF_DT);
  unsigned short* xg   = (unsigned short*)(ws + OFF_XG);
  unsigned short* obuf = (unsigned short*)(ws + OFF_XG);                        // after xg dead
  unsigned short* ybuf = (unsigned short*)(ws + OFF_XG) + (size_t)kM * kC;     // second half
  unsigned short* bufX = (unsigned short*)(ws + OFF_X);
  unsigned short* bufR = (unsigned short*)(ws + OFF_R);
  unsigned short* bufK = (unsigned short*)(ws + OFF_K);
  unsigned short* bufV = (unsigned short*)(ws + OFF_V);
  float*          Lbuf = (float*)(ws + OFF_L);
  float*          DsegP= (float*)(ws + OFF_TD1);

  float* outp  = (float*)d_out;
  float* lx    = outp + (size_t)kM * kC;
  float* stOut = lx + (size_t)kB * kC;

  dim3 blk(256);

  // weight prep
  trans_bf16<<<dim3(32, 32), blk, 0, stream>>>(Wr, Wrt, 2048, 2048);
  trans_bf16<<<dim3(32, 32), blk, 0, stream>>>(Wk, Wkt, 2048, 2048);
  trans_bf16<<<dim3(32, 32), blk, 0, stream>>>(Wv, Wvt, 2048, 2048);
  trans_bf16<<<dim3(32, 32), blk, 0, stream>>>(Wg, Wgt, 2048, 2048);
  trans_bf16<<<dim3(32, 32), blk, 0, stream>>>(Wo, Wot, 2048, 2048);
  trans_bf16<<<dim3(3, 32), blk, 0, stream>>>(w1, w1t, 2048, 160);
  trans_bf16<<<dim3(1, 32), blk, 0, stream>>>(tdw1, td1t, 2048, 64);
  trans_bf16<<<dim3(32, 1), blk, 0, stream>>>(tdw2, td2t, 64, 2048);
  trans_bf16<<<dim3(32, 3), blk, 0, stream>>>(w2, w2t, 160, 2048);

  // token shift + maa_x mix
  prep_x2<<<dim3(kM * kC / 4 / 256), blk, 0, stream>>>(x, shift, maax, bufX, lx);

  // t5 = tanh(xxx @ w1)
  gemm_k<128, 32, E_TANH><<<dim3(kM / 128, 5), blk, 0, stream>>>(bufX, w1t, t5, kM, 160, 2048);

  dim3 mgrid(kM / 64, kC / 64);
  constexpr int G256 = (kM / 256) * (kC / 256);
  constexpr size_t LDS256 = 131072;

  // fused 5-way mix: xw->X, xk->V, xv->R, xr->K, xg->XG  (reads x once)
  mix5f_k<<<mgrid, blk, 0, stream>>>(t5, w2t, x, shift, maaw, maak, maav, maar, maag,
                                     bufX, bufV, bufR, bufK, xg);
  // decay first stage: dtmp = tanh(xw @ tdw1)
  gemm_k<64, 64, E_TANH><<<dim3(kM / 64, 1), blk, 0, stream>>>(bufX, td1t, dtmp, kM, 64, 2048);

  // projections: k->X (xw dead), v->V (xk dead), r->R (xv dead), g->K (xr dead)
  gemm256_k<E_BF16><<<dim3(G256), dim3(512), LDS256, stream>>>(bufV, Wkt, bufX, kM, 2048, 2048);
  gemm256_k<E_BF16><<<dim3(G256), dim3(512), LDS256, stream>>>(bufR, Wvt, bufV, kM, 2048, 2048);
  gemm256_k<E_BF16><<<dim3(G256), dim3(512), LDS256, stream>>>(bufK, Wrt, bufR, kM, 2048, 2048);
  gemm256_k<E_SILU><<<dim3(G256), dim3(512), LDS256, stream>>>(xg, Wgt, bufK, kM, 2048, 2048);

  // WKV: pass1 (fused decay) -> combine -> pass2 (fused decay recompute; o -> obuf)
  wkv_local_k<<<dim3(kB * kH * SEGN), blk, 0, stream>>>(bufX, bufV, dtmp, td2t, tdec,
                                                        Lbuf, DsegP);
  wkv_combine_k<<<dim3(kB * kH), blk, 0, stream>>>(s0, DsegP, Lbuf, stOut);
  wkv_seg_k<<<dim3(kB * kH * SEGN), blk, 0, stream>>>(bufR, bufX, bufV, dtmp, td2t, tdec,
                                                      faaaa, Lbuf, obuf);

  // groupnorm * g -> y
  gn_k<<<dim3(kM * kH / 4), blk, 0, stream>>>(obuf, bufK, gnw, gnb, ybuf);

  // out = y @ Wo -> d_out
  gemm256_k<E_F32><<<dim3(G256), dim3(512), LDS256, stream>>>(ybuf, Wot, outp, kM, 2048, 2048);
}

// Round 20
// 1430.357 us; speedup vs baseline: 1.0039x; 1.0039x over previous
//
#include <hip/hip_runtime.h>
#include <hip/hip_bf16.h>
#include <stdint.h>

#define DEV __device__ __forceinline__

typedef __bf16 bf16x8 __attribute__((ext_vector_type(8)));
typedef float f32x4 __attribute__((ext_vector_type(4)));
typedef unsigned short u16x8 __attribute__((ext_vector_type(8)));

constexpr int kB = 4, kT = 4096, kC = 2048, kH = 32, kN = 64;
constexpr int kM = kB * kT; // 16384
constexpr int SEGN = 8, TSEG = kT / SEGN, CHN = TSEG / 64; // 8 segments x 512 t x 8 chunks

// ---------- bf16 helpers ----------
DEV float bfu2f(unsigned short u) {
  union { uint32_t i; float f; } x; x.i = ((uint32_t)u) << 16; return x.f;
}
DEV unsigned short f2bfu(float f) {
  union { float f; uint32_t i; } x; x.f = f;
  uint32_t r = x.i + 0x7FFFu + ((x.i >> 16) & 1u);
  return (unsigned short)(r >> 16);
}

DEV void gld16(const void* g, void* l) {
  __builtin_amdgcn_global_load_lds(
      (const __attribute__((address_space(1))) void*)g,
      (__attribute__((address_space(3))) void*)l, 16, 0, 0);
}

// swizzled byte offset within a [rows][128B] LDS tile (row-major, 64 bf16/row)
DEV int swzb(int row, int byteoff) { return (row << 7) + (byteoff ^ ((row & 7) << 4)); }

// ---------- generic transpose + fp32->bf16 ----------
__global__ __launch_bounds__(256) void trans_bf16(
    const float* __restrict__ in, unsigned short* __restrict__ out, int R, int Cn) {
  __shared__ __attribute__((aligned(16))) unsigned short tile[64][65];
  const int t = threadIdx.x;
  const int r0 = blockIdx.y * 64, c0 = blockIdx.x * 64;
  const int lr = t >> 6, lc = t & 63;
#pragma unroll
  for (int i = 0; i < 16; i++) {
    int rr = lr + i * 4;
    int gr = r0 + rr, gc = c0 + lc;
    if (gr < R && gc < Cn) tile[rr][lc] = f2bfu(in[(size_t)gr * Cn + gc]);
  }
  __syncthreads();
#pragma unroll
  for (int i = 0; i < 16; i++) {
    int cc = lr + i * 4;
    int gc = c0 + cc, gr = r0 + lc;
    if (gc < Cn && gr < R) out[(size_t)gc * R + gr] = tile[lc][cc];
  }
}

// ---------- prep: xxx = bf16(x + (shift(x)-x)*maa_x), lx copy ----------
__global__ __launch_bounds__(256) void prep_x2(
    const float* __restrict__ x, const float* __restrict__ shift,
    const float* __restrict__ maax,
    unsigned short* __restrict__ xxx, float* __restrict__ lx) {
  size_t i4 = ((size_t)blockIdx.x * 256 + threadIdx.x) * 4;
  int c = (int)(i4 & (kC - 1));
  size_t bt = i4 >> 11;
  int tt = (int)(bt & (kT - 1));
  int b = (int)(bt >> 12);
  float4 xv = *(const float4*)(x + i4);
  float4 pv = (tt == 0) ? *(const float4*)(shift + (size_t)b * kC + c)
                        : *(const float4*)(x + i4 - kC);
  float4 mx = *(const float4*)(maax + c);
  ushort4 o4;
  o4.x = f2bfu(xv.x + (pv.x - xv.x) * mx.x);
  o4.y = f2bfu(xv.y + (pv.y - xv.y) * mx.y);
  o4.z = f2bfu(xv.z + (pv.z - xv.z) * mx.z);
  o4.w = f2bfu(xv.w + (pv.w - xv.w) * mx.w);
  *(ushort4*)(xxx + i4) = o4;
  if (tt == kT - 1) *(float4*)(lx + (size_t)b * kC + c) = xv;
}

enum { E_F32 = 0, E_BF16 = 1, E_TANH = 2, E_SILU = 3 };

// ---------- small-shape bf16 MFMA GEMM (m97-style 128-tile) ----------
template <int BM, int BN, int EPI>
__global__ __launch_bounds__(256) void gemm_k(
    const unsigned short* __restrict__ A, const unsigned short* __restrict__ Bt,
    void* __restrict__ Cout, int M, int N, int K) {
  constexpr int WGM = (BM == 128 && BN == 128) ? 2 : (BM == 64 ? 2 : 4);
  constexpr int WGN = 4 / WGM;
  constexpr int WM = BM / WGM, WN = BN / WGN;
  constexpr int WR = WM / 16, WC = WN / 16;
  __shared__ __attribute__((aligned(16))) unsigned short As[BM * 32];
  __shared__ __attribute__((aligned(16))) unsigned short Bs[BN * 32];
  const int t = threadIdx.x, wid = t >> 6, l = t & 63;
  const int m0 = blockIdx.x * BM, n0 = blockIdx.y * BN;
  const int wm0 = (wid / WGN) * WM, wn0 = (wid % WGN) * WN;
  f32x4 acc[WR][WC];
#pragma unroll
  for (int i = 0; i < WR; i++)
#pragma unroll
    for (int j = 0; j < WC; j++) acc[i][j] = f32x4{0.f, 0.f, 0.f, 0.f};

  const int rowS = t >> 2, cbS = (t & 3) * 16;
  const char* Ab = (const char*)A;
  const char* Bb = (const char*)Bt;
  const int aoff = (wm0 + (l & 15)) * 32 + (l >> 4) * 8;
  const int boff = (wn0 + (l & 15)) * 32 + (l >> 4) * 8;

  for (int kt = 0; kt < K; kt += 32) {
#pragma unroll
    for (int ia = 0; ia < BM / 64; ia++)
      gld16(Ab + ((size_t)(m0 + ia * 64 + rowS) * K + kt) * 2 + cbS,
            (char*)As + ia * 4096 + wid * 1024);
    if constexpr (BN >= 64) {
#pragma unroll
      for (int ib = 0; ib < BN / 64; ib++)
        gld16(Bb + ((size_t)(n0 + ib * 64 + rowS) * K + kt) * 2 + cbS,
              (char*)Bs + ib * 4096 + wid * 1024);
    } else {
      if (t < BN * 4)
        gld16(Bb + ((size_t)(n0 + rowS) * K + kt) * 2 + cbS,
              (char*)Bs + wid * 1024);
    }
    __syncthreads();
    bf16x8 af[WR], bfv[WC];
#pragma unroll
    for (int mi = 0; mi < WR; mi++) af[mi] = *(const bf16x8*)(&As[aoff + mi * 512]);
#pragma unroll
    for (int ni = 0; ni < WC; ni++) bfv[ni] = *(const bf16x8*)(&Bs[boff + ni * 512]);
#pragma unroll
    for (int mi = 0; mi < WR; mi++)
#pragma unroll
      for (int ni = 0; ni < WC; ni++)
        acc[mi][ni] = __builtin_amdgcn_mfma_f32_16x16x32_bf16(af[mi], bfv[ni], acc[mi][ni], 0, 0, 0);
    __syncthreads();
  }

#pragma unroll
  for (int mi = 0; mi < WR; mi++) {
#pragma unroll
    for (int ni = 0; ni < WC; ni++) {
      int row = m0 + wm0 + mi * 16 + (l >> 4) * 4;
      int col = n0 + wn0 + ni * 16 + (l & 15);
#pragma unroll
      for (int j = 0; j < 4; j++) {
        float v = acc[mi][ni][j];
        size_t idx = (size_t)(row + j) * N + col;
        if constexpr (EPI == E_F32) ((float*)Cout)[idx] = v;
        else if constexpr (EPI == E_BF16) ((unsigned short*)Cout)[idx] = f2bfu(v);
        else if constexpr (EPI == E_TANH) ((unsigned short*)Cout)[idx] = f2bfu(tanhf(v));
        else if constexpr (EPI == E_SILU) ((unsigned short*)Cout)[idx] = f2bfu(v / (1.f + expf(-v)));
      }
    }
  }
}

// ---------- big GEMM: 256x256 tile, BK=64, 8 waves, m201-style 4-phase/K-tile ----------
// LDS: A = q*65536 + h*16384 ([128 rows][128B], swzb); B at +32768.
// Per tile: 4 phases x {ds_read || stage -> barrier -> lgkm(0) -> 16 MFMA -> barrier}.
// All 8 stage loads for tile T+1 issue at phases 0-1 of tile T (A first: HBM stream);
// single vmcnt(0) at phase 3 => ~2-3 phases of latency hiding. Never mid-loop drains.
#define GPH(PP, QQ, SKIND, KTB)                                                        \
  do {                                                                                 \
    const int aB_ = (PP) * 65536 + wr * 16384;                                         \
    const int bB_ = 32768 + (PP) * 65536 + bh * 16384;                                 \
    if ((QQ) == 0) {                                                                   \
      _Pragma("unroll")                                                                \
      for (int ni = 0; ni < 4; ni++) {                                                 \
        bfr[ni][0] = *(const bf16x8*)(lds + bB_ + bRow[ni] + bOffK0);                  \
        bfr[ni][1] = *(const bf16x8*)(lds + bB_ + bRow[ni] + bOffK1);                  \
      }                                                                                \
    }                                                                                  \
    bf16x8 a0k0_ = *(const bf16x8*)(lds + aB_ + (2 * (QQ)) * 2048 + aOffK0);           \
    bf16x8 a0k1_ = *(const bf16x8*)(lds + aB_ + (2 * (QQ)) * 2048 + aOffK1);           \
    bf16x8 a1k0_ = *(const bf16x8*)(lds + aB_ + (2 * (QQ) + 1) * 2048 + aOffK0);       \
    bf16x8 a1k1_ = *(const bf16x8*)(lds + aB_ + (2 * (QQ) + 1) * 2048 + aOffK1);       \
    if ((SKIND) == 1) {                                                                \
      const int d_ = ((PP) ^ 1) * 65536;                                               \
      gld16(pA0 + (KTB), lds + d_ + tid * 16);                                         \
      gld16(pA0 + (KTB) + (size_t)64 * kC * 2, lds + d_ + 8192 + tid * 16);            \
      gld16(pA1 + (KTB), lds + d_ + 16384 + tid * 16);                                 \
      gld16(pA1 + (KTB) + (size_t)64 * kC * 2, lds + d_ + 24576 + tid * 16);           \
    } else if ((SKIND) == 2) {                                                         \
      const int d_ = 32768 + (((PP) ^ 1) * 65536);                                     \
      gld16(pB0 + (KTB), lds + d_ + tid * 16);                                         \
      gld16(pB0 + (KTB) + (size_t)64 * kC * 2, lds + d_ + 8192 + tid * 16);            \
      gld16(pB1 + (KTB), lds + d_ + 16384 + tid * 16);                                 \
      gld16(pB1 + (KTB) + (size_t)64 * kC * 2, lds + d_ + 24576 + tid * 16);           \
    }                                                                                  \
    __builtin_amdgcn_s_barrier();                                                      \
    asm volatile("s_waitcnt lgkmcnt(0)" ::: "memory");                                 \
    __builtin_amdgcn_sched_barrier(0);                                                 \
    __builtin_amdgcn_s_setprio(1);                                                     \
    _Pragma("unroll")                                                                  \
    for (int ni = 0; ni < 4; ni++) {                                                   \
      acc[2 * (QQ)][ni] = __builtin_amdgcn_mfma_f32_16x16x32_bf16(a0k0_, bfr[ni][0], acc[2 * (QQ)][ni], 0, 0, 0);         \
      acc[2 * (QQ) + 1][ni] = __builtin_amdgcn_mfma_f32_16x16x32_bf16(a1k0_, bfr[ni][0], acc[2 * (QQ) + 1][ni], 0, 0, 0); \
      acc[2 * (QQ)][ni] = __builtin_amdgcn_mfma_f32_16x16x32_bf16(a0k1_, bfr[ni][1], acc[2 * (QQ)][ni], 0, 0, 0);         \
      acc[2 * (QQ) + 1][ni] = __builtin_amdgcn_mfma_f32_16x16x32_bf16(a1k1_, bfr[ni][1], acc[2 * (QQ) + 1][ni], 0, 0, 0); \
    }                                                                                  \
    __builtin_amdgcn_s_setprio(0);                                                     \
    if ((QQ) == 3) {                                                                   \
      asm volatile("s_waitcnt vmcnt(0)" ::: "memory");                                 \
      __builtin_amdgcn_sched_barrier(0);                                               \
    }                                                                                  \
    __builtin_amdgcn_s_barrier();                                                      \
    __builtin_amdgcn_sched_barrier(0);                                                 \
  } while (0)

template <int EPI>
__global__ __launch_bounds__(512, 1) void gemm256_k(
    const unsigned short* __restrict__ A, const unsigned short* __restrict__ Bt,
    void* __restrict__ Cout, int M, int N, int K) {
  extern __shared__ __attribute__((aligned(16))) char lds[];
  const int tid = threadIdx.x, wid = tid >> 6, l = tid & 63;
  const int fr = l & 15, fq = l >> 4;
  const int wr = wid >> 2, wc = wid & 3;
  const int bh = wc >> 1;

  // XCD mapping: each XCD owns an (mtiles/8)-tall M-slab; N walks fastest.
  const int mtiles = M >> 8, ntiles = N >> 8;
  const int slab = mtiles >> 3;
  const int xcd = blockIdx.x & 7, loc = blockIdx.x >> 3;
  const int m0 = (xcd * slab + loc / ntiles) * 256;
  const int n0 = (loc % ntiles) * 256;

  // hoisted stage-source pointers: r = tid>>3 (64-row sweep), cb pre-swizzled
  const int sr = tid >> 3;
  const int scb = ((tid & 7) * 16) ^ ((sr & 7) << 4);
  const char* pA0 = (const char*)A + (size_t)(m0 + sr) * K * 2 + scb;
  const char* pA1 = (const char*)A + (size_t)(m0 + 128 + sr) * K * 2 + scb;
  const char* pB0 = (const char*)Bt + (size_t)(n0 + sr) * K * 2 + scb;
  const char* pB1 = (const char*)Bt + (size_t)(n0 + 128 + sr) * K * 2 + scb;

  // hoisted ds_read byte offsets (swizzle XOR is lane-constant)
  const int xorv = (fr & 7) << 4;
  const int aOffK0 = fr * 128 + ((fq * 16) ^ xorv);
  const int aOffK1 = fr * 128 + ((64 + fq * 16) ^ xorv);
  const int bOffK0 = aOffK0, bOffK1 = aOffK1;
  int bRow[4];
#pragma unroll
  for (int ni = 0; ni < 4; ni++) bRow[ni] = ((wc & 1) * 64 + ni * 16) * 128;

  f32x4 acc[8][4];
#pragma unroll
  for (int i = 0; i < 8; i++)
#pragma unroll
    for (int j = 0; j < 4; j++) acc[i][j] = f32x4{0.f, 0.f, 0.f, 0.f};
  bf16x8 bfr[4][2];

  const int KT = K >> 6;
  // prologue: stage tile 0 into buf0 (8 loads), drain, barrier
  {
    gld16(pA0, lds + tid * 16);
    gld16(pA0 + (size_t)64 * kC * 2, lds + 8192 + tid * 16);
    gld16(pA1, lds + 16384 + tid * 16);
    gld16(pA1 + (size_t)64 * kC * 2, lds + 24576 + tid * 16);
    gld16(pB0, lds + 32768 + tid * 16);
    gld16(pB0 + (size_t)64 * kC * 2, lds + 32768 + 8192 + tid * 16);
    gld16(pB1, lds + 32768 + 16384 + tid * 16);
    gld16(pB1 + (size_t)64 * kC * 2, lds + 32768 + 24576 + tid * 16);
    asm volatile("s_waitcnt vmcnt(0)" ::: "memory");
    __builtin_amdgcn_s_barrier();
    __builtin_amdgcn_sched_barrier(0);
  }

  for (int T = 0; T < KT; ++T) {
    const int p = T & 1;
    const int st = (T + 1 < KT) ? 1 : 0;
    const int ktb = (T + 1) * 128;
    GPH(p, 0, st ? 1 : 0, ktb);
    GPH(p, 1, st ? 2 : 0, ktb);
    GPH(p, 2, 0, 0);
    GPH(p, 3, 0, 0);
  }

#pragma unroll
  for (int mi = 0; mi < 8; mi++)
#pragma unroll
    for (int ni = 0; ni < 4; ni++) {
      int row = m0 + wr * 128 + mi * 16 + fq * 4;
      int col = n0 + wc * 64 + ni * 16 + fr;
#pragma unroll
      for (int j = 0; j < 4; j++) {
        float v = acc[mi][ni][j];
        size_t idx = (size_t)(row + j) * N + col;
        if constexpr (EPI == E_F32) ((float*)Cout)[idx] = v;
        else if constexpr (EPI == E_BF16) ((unsigned short*)Cout)[idx] = f2bfu(v);
        else if constexpr (EPI == E_SILU) ((unsigned short*)Cout)[idx] = f2bfu(v / (1.f + expf(-v)));
      }
    }
}

// ---------- five-feature mix: direct-global fragments, single f32 bounce tile ----------
__global__ __launch_bounds__(256) void mix5f_k(
    const unsigned short* __restrict__ t5, const unsigned short* __restrict__ w2t,
    const float* __restrict__ x, const float* __restrict__ shift,
    const float* __restrict__ maaw, const float* __restrict__ maak,
    const float* __restrict__ maav, const float* __restrict__ maar,
    const float* __restrict__ maag,
    unsigned short* __restrict__ xw, unsigned short* __restrict__ xk,
    unsigned short* __restrict__ xvo, unsigned short* __restrict__ xr,
    unsigned short* __restrict__ xg) {
  __shared__ __attribute__((aligned(16))) float tile[64][68];   // 17408B
  const int t = threadIdx.x, wid = t >> 6, l = t & 63;
  const int m0 = blockIdx.x * 64, n0 = blockIdx.y * 64;
  const int wm0 = (wid >> 1) * 32, wn0 = (wid & 1) * 32;
  const int fr = l & 15, fq = l >> 4;

  const unsigned short* pa0 = t5 + (size_t)(m0 + wm0 + fr) * 160 + fq * 8;
  const unsigned short* pa1 = t5 + (size_t)(m0 + wm0 + 16 + fr) * 160 + fq * 8;
  const unsigned short* pb0 = w2t + (size_t)(n0 + wn0 + fr) * 160 + fq * 8;
  const unsigned short* pb1 = w2t + (size_t)(n0 + wn0 + 16 + fr) * 160 + fq * 8;

  const int rrow = m0 + (t >> 2);
  const int c0 = (t & 3) * 16;
  const size_t base = (size_t)rrow * kC + n0 + c0;
  float xreg[16], dreg[16];
  {
    const int tt = rrow & (kT - 1);
    const float* pvp = (tt == 0) ? (shift + (size_t)(rrow >> 12) * kC + n0 + c0)
                                 : (x + base - kC);
#pragma unroll
    for (int q = 0; q < 4; q++) {
      float4 xv4 = *(const float4*)(x + base + q * 4);
      float4 pv4 = *(const float4*)(pvp + q * 4);
      xreg[q * 4 + 0] = xv4.x; dreg[q * 4 + 0] = pv4.x - xv4.x;
      xreg[q * 4 + 1] = xv4.y; dreg[q * 4 + 1] = pv4.y - xv4.y;
      xreg[q * 4 + 2] = xv4.z; dreg[q * 4 + 2] = pv4.z - xv4.z;
      xreg[q * 4 + 3] = xv4.w; dreg[q * 4 + 3] = pv4.w - xv4.w;
    }
  }

  unsigned short* outs[5] = { xw, xk, xvo, xr, xg };
  const float* maas[5] = { maaw, maak, maav, maar, maag };
#pragma unroll
  for (int f = 0; f < 5; f++) {
    bf16x8 a0 = *(const bf16x8*)(pa0 + f * 32);
    bf16x8 a1 = *(const bf16x8*)(pa1 + f * 32);
    bf16x8 b0 = *(const bf16x8*)(pb0 + f * 32);
    bf16x8 b1 = *(const bf16x8*)(pb1 + f * 32);
    f32x4 ac00 = __builtin_amdgcn_mfma_f32_16x16x32_bf16(a0, b0, f32x4{0.f, 0.f, 0.f, 0.f}, 0, 0, 0);
    f32x4 ac01 = __builtin_amdgcn_mfma_f32_16x16x32_bf16(a0, b1, f32x4{0.f, 0.f, 0.f, 0.f}, 0, 0, 0);
    f32x4 ac10 = __builtin_amdgcn_mfma_f32_16x16x32_bf16(a1, b0, f32x4{0.f, 0.f, 0.f, 0.f}, 0, 0, 0);
    f32x4 ac11 = __builtin_amdgcn_mfma_f32_16x16x32_bf16(a1, b1, f32x4{0.f, 0.f, 0.f, 0.f}, 0, 0, 0);
    __syncthreads();   // prev feature's tile reads done (WAR)
#pragma unroll
    for (int j = 0; j < 4; j++) {
      tile[wm0 + fq * 4 + j][wn0 + fr]            = ac00[j];
      tile[wm0 + fq * 4 + j][wn0 + 16 + fr]       = ac01[j];
      tile[wm0 + 16 + fq * 4 + j][wn0 + fr]       = ac10[j];
      tile[wm0 + 16 + fq * 4 + j][wn0 + 16 + fr]  = ac11[j];
    }
    __syncthreads();   // tile ready
    const float* mp = maas[f] + n0 + c0;
    u16x8 o0, o1;
#pragma unroll
    for (int q = 0; q < 4; q++) {
      f32x4 m4 = *(const f32x4*)&tile[t >> 2][c0 + q * 4];
      float4 ma4 = *(const float4*)(mp + q * 4);
      float mv[4] = { ma4.x, ma4.y, ma4.z, ma4.w };
#pragma unroll
      for (int e = 0; e < 4; e++) {
        int i = q * 4 + e;
        unsigned short r = f2bfu(xreg[i] + dreg[i] * (mv[e] + m4[e]));
        if (i < 8) o0[i] = r; else o1[i - 8] = r;
      }
    }
    *(u16x8*)(outs[f] + base) = o0;
    *(u16x8*)(outs[f] + base + 8) = o1;
  }
}

// ---------- WKV pass 1: fused decay compute + local state (no edec materialization) ----------
__global__ __launch_bounds__(256) void wkv_local_k(
    const unsigned short* __restrict__ kb, const unsigned short* __restrict__ vb,
    const unsigned short* __restrict__ dtmp, const unsigned short* __restrict__ td2t,
    const float* __restrict__ tdec,
    float* __restrict__ Lbuf, float* __restrict__ Dseg) {
  const int bid = blockIdx.x;
  const int bh = bid >> 3, seg = bid & 7;
  const int h = bh & 31, b = bh >> 5;
  const int tid = threadIdx.x, w = tid >> 6, l = tid & 63;
  __shared__ __attribute__((aligned(16))) char arena[32768];
  char* KQks = arena;
  char* Vt   = arena + 8192;
  float* EdB = (float*)arena;
  char* TdB  = arena + 16384;
  char* DtA  = arena + 24576;
  __shared__ float segp[4][64];
  __shared__ float DLs[64];
  __shared__ float tdf[64];

  const int fr = l & 15, fq = l >> 4;
  f32x4 Sreg[4];
#pragma unroll
  for (int ni = 0; ni < 4; ni++) Sreg[ni] = f32x4{0.f, 0.f, 0.f, 0.f};

  {
    int r1 = tid >> 3, r2 = 32 + r1;
    int cb1 = ((tid & 7) * 16) ^ ((r1 & 7) << 4);
    int cb2 = ((tid & 7) * 16) ^ ((r2 & 7) << 4);
    gld16((const char*)td2t + (size_t)(h * 64 + r1) * 128 + cb1, TdB + w * 1024);
    gld16((const char*)td2t + (size_t)(h * 64 + r2) * 128 + cb2, TdB + 4096 + w * 1024);
    if (tid < 64) tdf[tid] = tdec[h * 64 + tid];
  }

  float dtot = 1.f;
  float kv[16], vv[16];
  {
    size_t g = ((size_t)b * kT + seg * TSEG + w * 16) * kC + h * 64 + l;
#pragma unroll
    for (int i = 0; i < 16; i++) {
      kv[i] = bfu2f(kb[g]); vv[i] = bfu2f(vb[g]);
      g += kC;
    }
  }

  for (int ch = 0; ch < CHN; ++ch) {
    const size_t gt0 = (size_t)b * kT + seg * TSEG + ch * 64;
    {
      int r1 = tid >> 3, r2 = 32 + r1;
      int cb1 = ((tid & 7) * 16) ^ ((r1 & 7) << 4);
      int cb2 = ((tid & 7) * 16) ^ ((r2 & 7) << 4);
      gld16((const char*)dtmp + (gt0 + r1) * 128 + cb1, DtA + w * 1024);
      gld16((const char*)dtmp + (gt0 + r2) * 128 + cb2, DtA + 4096 + w * 1024);
    }
    __syncthreads();  // B0

    f32x4 dacc[4];
    {
      bf16x8 af0 = *(const bf16x8*)(DtA + swzb(w * 16 + fr, fq * 16));
      bf16x8 af1 = *(const bf16x8*)(DtA + swzb(w * 16 + fr, fq * 16 + 64));
#pragma unroll
      for (int nj = 0; nj < 4; nj++) {
        bf16x8 b0 = *(const bf16x8*)(TdB + swzb(nj * 16 + fr, fq * 16));
        bf16x8 b1 = *(const bf16x8*)(TdB + swzb(nj * 16 + fr, fq * 16 + 64));
        dacc[nj] = __builtin_amdgcn_mfma_f32_16x16x32_bf16(af0, b0, f32x4{0.f, 0.f, 0.f, 0.f}, 0, 0, 0);
        dacc[nj] = __builtin_amdgcn_mfma_f32_16x16x32_bf16(af1, b1, dacc[nj], 0, 0, 0);
      }
    }
#pragma unroll
    for (int nj = 0; nj < 4; nj++) {
      float tv = tdf[nj * 16 + fr];
#pragma unroll
      for (int j = 0; j < 4; j++)
        EdB[(w * 16 + fq * 4 + j) * 64 + nj * 16 + fr] = expf(-expf(dacc[nj][j] + tv));
    }
    float dvv[16];
    float p = 1.f;
#pragma unroll
    for (int i = 0; i < 16; i++) {
      float d = EdB[(w * 16 + i) * 64 + l];
      dvv[i] = d; p *= d;
    }
    segp[w][l] = p;
    __syncthreads();  // B2

    float pre = 1.f;
    if (w > 0) pre *= segp[0][l];
    if (w > 1) pre *= segp[1][l];
    if (w > 2) pre *= segp[2][l];
    if (w == 3) DLs[l] = pre * p;

    unsigned short kqrow[16], vtrow[16];
    float run = pre;
#pragma unroll
    for (int i = 0; i < 16; i++) {
      run *= dvv[i];
      kqrow[i] = f2bfu(kv[i] / run);
      vtrow[i] = f2bfu(vv[i]);
    }
    {
      u16x8 q0, q1, v0, v1;
#pragma unroll
      for (int j = 0; j < 8; j++) { q0[j] = kqrow[j]; q1[j] = kqrow[j + 8]; v0[j] = vtrow[j]; v1[j] = vtrow[j + 8]; }
      *(u16x8*)(KQks + swzb(l, w * 32)) = q0;
      *(u16x8*)(KQks + swzb(l, w * 32 + 16)) = q1;
      *(u16x8*)(Vt + swzb(l, w * 32)) = v0;
      *(u16x8*)(Vt + swzb(l, w * 32 + 16)) = v1;
    }
    if (ch < CHN - 1) {
      size_t g = ((size_t)b * kT + seg * TSEG + (ch + 1) * 64 + w * 16) * kC + h * 64 + l;
#pragma unroll
      for (int i = 0; i < 16; i++) {
        kv[i] = bfu2f(kb[g]); vv[i] = bfu2f(vb[g]);
        g += kC;
      }
    }
    __syncthreads();  // B3

    bf16x8 kA0 = *(const bf16x8*)(KQks + swzb(w * 16 + fr, fq * 16));
    bf16x8 kA1 = *(const bf16x8*)(KQks + swzb(w * 16 + fr, fq * 16 + 64));
    f32x4 kvacc[4];
#pragma unroll
    for (int ni = 0; ni < 4; ni++) {
      bf16x8 bv0 = *(const bf16x8*)(Vt + swzb(ni * 16 + fr, fq * 16));
      bf16x8 bv1 = *(const bf16x8*)(Vt + swzb(ni * 16 + fr, fq * 16 + 64));
      kvacc[ni] = __builtin_amdgcn_mfma_f32_16x16x32_bf16(kA0, bv0, f32x4{0.f, 0.f, 0.f, 0.f}, 0, 0, 0);
      kvacc[ni] = __builtin_amdgcn_mfma_f32_16x16x32_bf16(kA1, bv1, kvacc[ni], 0, 0, 0);
    }
    float dlj[4];
#pragma unroll
    for (int j = 0; j < 4; j++) dlj[j] = DLs[w * 16 + fq * 4 + j];
#pragma unroll
    for (int ni = 0; ni < 4; ni++)
#pragma unroll
      for (int j = 0; j < 4; j++)
        Sreg[ni][j] = (Sreg[ni][j] + kvacc[ni][j]) * dlj[j];
    dtot *= DLs[l];
  }

  float* Lp = Lbuf + (size_t)bid * 4096;
#pragma unroll
  for (int ni = 0; ni < 4; ni++)
#pragma unroll
    for (int j = 0; j < 4; j++)
      Lp[(size_t)(w * 16 + fq * 4 + j) * 64 + ni * 16 + fr] = Sreg[ni][j];
  if (w == 0) Dseg[(size_t)bid * 64 + l] = dtot;
}

// ---------- WKV combine ----------
__global__ __launch_bounds__(256) void wkv_combine_k(
    const float* __restrict__ s0, const float* __restrict__ Dseg,
    float* __restrict__ Lbuf, float* __restrict__ sOut) {
  const int bh = blockIdx.x, tid = threadIdx.x;
  const int k = tid >> 2, v0 = (tid & 3) * 16;
  float4 s[4];
  const float* sp = s0 + (size_t)bh * 4096 + (size_t)k * 64 + v0;
#pragma unroll
  for (int q = 0; q < 4; q++) s[q] = ((const float4*)sp)[q];
  for (int seg = 0; seg < SEGN; ++seg) {
    size_t idx = (size_t)bh * SEGN + seg;
    float d = Dseg[idx * 64 + k];
    float* Lp = Lbuf + idx * 4096 + (size_t)k * 64 + v0;
#pragma unroll
    for (int q = 0; q < 4; q++) {
      float4 lq = ((float4*)Lp)[q];
      ((float4*)Lp)[q] = s[q];
      s[q].x = d * s[q].x + lq.x; s[q].y = d * s[q].y + lq.y;
      s[q].z = d * s[q].z + lq.z; s[q].w = d * s[q].w + lq.w;
    }
  }
  float* op = sOut + (size_t)bh * 4096 + (size_t)k * 64 + v0;
#pragma unroll
  for (int q = 0; q < 4; q++) ((float4*)op)[q] = s[q];
}

// ---------- WKV pass 2: fused decay recompute (no edec read), o -> HBM ----------
__global__ __launch_bounds__(256) void wkv_seg_k(
    const unsigned short* __restrict__ rb, const unsigned short* __restrict__ kb,
    const unsigned short* __restrict__ vb,
    const unsigned short* __restrict__ dtmp, const unsigned short* __restrict__ td2t,
    const float* __restrict__ tdec,
    const float* __restrict__ uf, const float* __restrict__ Sini,
    unsigned short* __restrict__ o) {
  const int bid = blockIdx.x;
  const int bh = bid >> 3, seg = bid & 7;
  const int h = bh & 31, b = bh >> 5;
  const int tid = threadIdx.x, w = tid >> 6, l = tid & 63;
  __shared__ __attribute__((aligned(16))) char arena[65536];
  char* RQ   = arena;
  char* KQsk = arena + 8192;
  char* KQks = arena + 16384;
  char* Vt   = arena + 24576;
  char* Pl   = arena + 32768;
  char* S0T  = arena + 40960;
  char* RU   = arena + 49152;
  char* Ksk  = arena + 57344;
  float* EdB = (float*)arena;
  char* DtA  = RU;
  char* TdB  = Ksk;
  __shared__ float segp[4][64];
  __shared__ float DLs[64];
  __shared__ float tdf[64];

  const float uu = uf[h * 64 + l];
  const int fr = l & 15, fq = l >> 4;
  if (tid < 64) tdf[tid] = tdec[h * 64 + tid];

  f32x4 Sreg[4];
#pragma unroll
  for (int ni = 0; ni < 4; ni++)
#pragma unroll
    for (int j = 0; j < 4; j++) {
      int kk2 = w * 16 + fq * 4 + j, vv2 = ni * 16 + fr;
      float sv = Sini[(size_t)bid * 4096 + (size_t)kk2 * 64 + vv2];
      Sreg[ni][j] = sv;
      *(unsigned short*)(S0T + swzb(vv2, kk2 * 2)) = f2bfu(sv);
    }
  __syncthreads();

  float rv[16], kv[16], vv[16];
  {
    size_t g = ((size_t)b * kT + seg * TSEG + w * 16) * kC + h * 64 + l;
#pragma unroll
    for (int i = 0; i < 16; i++) {
      rv[i] = bfu2f(rb[g]); kv[i] = bfu2f(kb[g]); vv[i] = bfu2f(vb[g]);
      g += kC;
    }
  }

  const int r1s = tid >> 3, r2s = 32 + r1s;
  const int cb1 = ((tid & 7) * 16) ^ ((r1s & 7) << 4);
  const int cb2 = ((tid & 7) * 16) ^ ((r2s & 7) << 4);

  for (int ch = 0; ch < CHN; ++ch) {
    const size_t gt0 = (size_t)b * kT + seg * TSEG + ch * 64;
    gld16((const char*)dtmp + (gt0 + r1s) * 128 + cb1, DtA + w * 1024);
    gld16((const char*)dtmp + (gt0 + r2s) * 128 + cb2, DtA + 4096 + w * 1024);
    gld16((const char*)td2t + (size_t)(h * 64 + r1s) * 128 + cb1, TdB + w * 1024);
    gld16((const char*)td2t + (size_t)(h * 64 + r2s) * 128 + cb2, TdB + 4096 + w * 1024);
    __syncthreads();   // S1

    f32x4 dacc[4];
    {
      bf16x8 af0 = *(const bf16x8*)(DtA + swzb(w * 16 + fr, fq * 16));
      bf16x8 af1 = *(const bf16x8*)(DtA + swzb(w * 16 + fr, fq * 16 + 64));
#pragma unroll
      for (int nj = 0; nj < 4; nj++) {
        bf16x8 b0 = *(const bf16x8*)(TdB + swzb(nj * 16 + fr, fq * 16));
        bf16x8 b1 = *(const bf16x8*)(TdB + swzb(nj * 16 + fr, fq * 16 + 64));
        dacc[nj] = __builtin_amdgcn_mfma_f32_16x16x32_bf16(af0, b0, f32x4{0.f, 0.f, 0.f, 0.f}, 0, 0, 0);
        dacc[nj] = __builtin_amdgcn_mfma_f32_16x16x32_bf16(af1, b1, dacc[nj], 0, 0, 0);
      }
    }
#pragma unroll
    for (int nj = 0; nj < 4; nj++) {
      float tv = tdf[nj * 16 + fr];
#pragma unroll
      for (int j = 0; j < 4; j++)
        EdB[(w * 16 + fq * 4 + j) * 64 + nj * 16 + fr] = expf(-expf(dacc[nj][j] + tv));
    }
    float dv[16];
    float p = 1.f;
#pragma unroll
    for (int i = 0; i < 16; i++) {
      dv[i] = EdB[(w * 16 + i) * 64 + l];
      p *= dv[i];
    }
    segp[w][l] = p;
    __syncthreads();   // S2

    float pre = 1.f;
    if (w > 0) pre *= segp[0][l];
    if (w > 1) pre *= segp[1][l];
    if (w > 2) pre *= segp[2][l];
    if (w == 3) DLs[l] = pre * p;

    unsigned short kqrow[16], vtrow[16];
    float run = pre;
#pragma unroll
    for (int i = 0; i < 16; i++) {
      int t = w * 16 + i;
      float rq = rv[i] * run;
      run *= dv[i];
      float kq = kv[i] / run;
      *(unsigned short*)(RQ + swzb(t, l * 2)) = f2bfu(rq);
      *(unsigned short*)(RU + swzb(t, l * 2)) = f2bfu(rv[i] * uu);
      *(unsigned short*)(Ksk + swzb(t, l * 2)) = f2bfu(kv[i]);
      unsigned short kqu = f2bfu(kq);
      *(unsigned short*)(KQsk + swzb(t, l * 2)) = kqu;
      kqrow[i] = kqu;
      vtrow[i] = f2bfu(vv[i]);
    }
    {
      u16x8 q0, q1, v0, v1;
#pragma unroll
      for (int j = 0; j < 8; j++) { q0[j] = kqrow[j]; q1[j] = kqrow[j + 8]; v0[j] = vtrow[j]; v1[j] = vtrow[j + 8]; }
      *(u16x8*)(KQks + swzb(l, w * 32)) = q0;
      *(u16x8*)(KQks + swzb(l, w * 32 + 16)) = q1;
      *(u16x8*)(Vt + swzb(l, w * 32)) = v0;
      *(u16x8*)(Vt + swzb(l, w * 32 + 16)) = v1;
    }

    if (ch < CHN - 1) {
      size_t g = ((size_t)b * kT + seg * TSEG + (ch + 1) * 64 + w * 16) * kC + h * 64 + l;
#pragma unroll
      for (int i = 0; i < 16; i++) {
        rv[i] = bfu2f(rb[g]); kv[i] = bfu2f(kb[g]); vv[i] = bfu2f(vb[g]);
        g += kC;
      }
    }
    __syncthreads();   // S3

    bf16x8 a0 = *(const bf16x8*)(RQ + swzb(w * 16 + fr, fq * 16));
    bf16x8 a1 = *(const bf16x8*)(RQ + swzb(w * 16 + fr, fq * 16 + 64));
    f32x4 pacc[4];
#pragma unroll
    for (int ni = 0; ni < 4; ni++) {
      bf16x8 b0 = *(const bf16x8*)(KQsk + swzb(ni * 16 + fr, fq * 16));
      bf16x8 b1 = *(const bf16x8*)(KQsk + swzb(ni * 16 + fr, fq * 16 + 64));
      pacc[ni] = __builtin_amdgcn_mfma_f32_16x16x32_bf16(a0, b0, f32x4{0.f, 0.f, 0.f, 0.f}, 0, 0, 0);
      pacc[ni] = __builtin_amdgcn_mfma_f32_16x16x32_bf16(a1, b1, pacc[ni], 0, 0, 0);
    }
    f32x4 dacc2;
    {
      bf16x8 ru0 = *(const bf16x8*)(RU + swzb(w * 16 + fr, fq * 16));
      bf16x8 ru1 = *(const bf16x8*)(RU + swzb(w * 16 + fr, fq * 16 + 64));
      bf16x8 kb0 = *(const bf16x8*)(Ksk + swzb(w * 16 + fr, fq * 16));
      bf16x8 kb1 = *(const bf16x8*)(Ksk + swzb(w * 16 + fr, fq * 16 + 64));
      dacc2 = __builtin_amdgcn_mfma_f32_16x16x32_bf16(ru0, kb0, f32x4{0.f, 0.f, 0.f, 0.f}, 0, 0, 0);
      dacc2 = __builtin_amdgcn_mfma_f32_16x16x32_bf16(ru1, kb1, dacc2, 0, 0, 0);
    }
    float dg[4];
#pragma unroll
    for (int j = 0; j < 4; j++) dg[j] = __shfl(dacc2[j], fq * 20 + j, 64);
#pragma unroll
    for (int ni = 0; ni < 4; ni++)
#pragma unroll
      for (int j = 0; j < 4; j++) {
        int row = w * 16 + fq * 4 + j, col = ni * 16 + fr;
        float pv = pacc[ni][j];
        pv = (col < row) ? pv : ((col == row) ? dg[j] : 0.f);
        *(unsigned short*)(Pl + swzb(row, col * 2)) = f2bfu(pv);
      }
    __syncthreads();   // S4

    bf16x8 pA0 = *(const bf16x8*)(Pl + swzb(w * 16 + fr, fq * 16));
    bf16x8 pA1 = *(const bf16x8*)(Pl + swzb(w * 16 + fr, fq * 16 + 64));
    bf16x8 kA0 = *(const bf16x8*)(KQks + swzb(w * 16 + fr, fq * 16));
    bf16x8 kA1 = *(const bf16x8*)(KQks + swzb(w * 16 + fr, fq * 16 + 64));
    f32x4 oacc[4], kvacc[4];
#pragma unroll
    for (int ni = 0; ni < 4; ni++) {
      bf16x8 bv0 = *(const bf16x8*)(Vt + swzb(ni * 16 + fr, fq * 16));
      bf16x8 bv1 = *(const bf16x8*)(Vt + swzb(ni * 16 + fr, fq * 16 + 64));
      bf16x8 bs0 = *(const bf16x8*)(S0T + swzb(ni * 16 + fr, fq * 16));
      bf16x8 bs1 = *(const bf16x8*)(S0T + swzb(ni * 16 + fr, fq * 16 + 64));
      oacc[ni] = __builtin_amdgcn_mfma_f32_16x16x32_bf16(pA0, bv0, f32x4{0.f, 0.f, 0.f, 0.f}, 0, 0, 0);
      oacc[ni] = __builtin_amdgcn_mfma_f32_16x16x32_bf16(pA1, bv1, oacc[ni], 0, 0, 0);
      oacc[ni] = __builtin_amdgcn_mfma_f32_16x16x32_bf16(a0, bs0, oacc[ni], 0, 0, 0);
      oacc[ni] = __builtin_amdgcn_mfma_f32_16x16x32_bf16(a1, bs1, oacc[ni], 0, 0, 0);
      kvacc[ni] = __builtin_amdgcn_mfma_f32_16x16x32_bf16(kA0, bv0, f32x4{0.f, 0.f, 0.f, 0.f}, 0, 0, 0);
      kvacc[ni] = __builtin_amdgcn_mfma_f32_16x16x32_bf16(kA1, bv1, kvacc[ni], 0, 0, 0);
    }
    size_t obase = gt0 * kC + h * 64;
#pragma unroll
    for (int ni = 0; ni < 4; ni++)
#pragma unroll
      for (int j = 0; j < 4; j++)
        o[obase + (size_t)(w * 16 + fq * 4 + j) * kC + ni * 16 + fr] = f2bfu(oacc[ni][j]);
    __syncthreads();   // S5

    float dlj[4];
#pragma unroll
    for (int j = 0; j < 4; j++) dlj[j] = DLs[w * 16 + fq * 4 + j];
#pragma unroll
    for (int ni = 0; ni < 4; ni++)
#pragma unroll
      for (int j = 0; j < 4; j++) {
        int kk2 = w * 16 + fq * 4 + j, vv2 = ni * 16 + fr;
        float sn = (Sreg[ni][j] + kvacc[ni][j]) * dlj[j];
        Sreg[ni][j] = sn;
        *(unsigned short*)(S0T + swzb(vv2, kk2 * 2)) = f2bfu(sn);
      }
  }
}

// ---------- GroupNorm over N=64 per (b,t,h), times g, -> bf16 ----------
__global__ __launch_bounds__(256) void gn_k(
    const unsigned short* __restrict__ o, const unsigned short* __restrict__ gb,
    const float* __restrict__ gnw, const float* __restrict__ gnb,
    unsigned short* __restrict__ y) {
  int gi = blockIdx.x * 4 + (threadIdx.x >> 6);
  int j = threadIdx.x & 63;
  int bt = gi >> 5, h = gi & 31;
  size_t idx = (size_t)bt * kC + h * 64 + j;
  float val = bfu2f(o[idx]);
  float s = val, s2 = val * val;
#pragma unroll
  for (int m = 1; m < 64; m <<= 1) {
    s += __shfl_xor(s, m, 64);
    s2 += __shfl_xor(s2, m, 64);
  }
  float mu = s * 0.015625f;
  float var = s2 * 0.015625f - mu * mu;
  float rs = rsqrtf(var + 6.4e-4f);
  float on = (val - mu) * rs * gnw[h * 64 + j] + gnb[h * 64 + j];
  y[idx] = f2bfu(on * bfu2f(gb[idx]));
}

// ---------- workspace layout ----------
constexpr size_t SZW     = (size_t)2048 * 2048 * 2;
constexpr size_t OFF_WRT = 0;
constexpr size_t OFF_WKT = 1 * SZW;
constexpr size_t OFF_WVT = 2 * SZW;
constexpr size_t OFF_WGT = 3 * SZW;
constexpr size_t OFF_WOT = 4 * SZW;
constexpr size_t OFF_W1T = 5 * SZW;
constexpr size_t OFF_W2T = OFF_W1T + (size_t)160 * 2048 * 2;
constexpr size_t OFF_TD1 = OFF_W2T + (size_t)2048 * 160 * 2;     // later Dseg f32
constexpr size_t OFF_TD2 = OFF_TD1 + (size_t)64 * 2048 * 2;
constexpr size_t OFF_T5  = OFF_TD2 + (size_t)2048 * 64 * 2;
constexpr size_t OFF_DT  = OFF_T5 + (size_t)kM * 160 * 2;
constexpr size_t OFF_XG  = OFF_DT + (size_t)kM * 64 * 2;         // xg bf16; later o bf16 + y bf16
constexpr size_t OFF_X   = OFF_XG + (size_t)kM * kC * 4;         // xxx/xw; k
constexpr size_t OFF_R   = OFF_X + (size_t)kM * kC * 2;          // xv; r
constexpr size_t OFF_K   = OFF_R + (size_t)kM * kC * 2;          // xr; g
constexpr size_t OFF_V   = OFF_K + (size_t)kM * kC * 2;          // xk; v
constexpr size_t OFF_L   = OFF_WRT;

extern "C" void kernel_launch(void* const* d_in, const int* in_sizes, int n_in,
                              void* d_out, int out_size, void* d_ws, size_t ws_size,
                              hipStream_t stream) {
  const float* x     = (const float*)d_in[0];
  const float* shift = (const float*)d_in[1];
  const float* s0    = (const float*)d_in[2];
  const float* maax  = (const float*)d_in[3];
  const float* maaw  = (const float*)d_in[4];
  const float* maak  = (const float*)d_in[5];
  const float* maav  = (const float*)d_in[6];
  const float* maar  = (const float*)d_in[7];
  const float* maag  = (const float*)d_in[8];
  const float* w1    = (const float*)d_in[9];
  const float* w2    = (const float*)d_in[10];
  const float* tdec  = (const float*)d_in[11];
  const float* tdw1  = (const float*)d_in[12];
  const float* tdw2  = (const float*)d_in[13];
  const float* faaaa = (const float*)d_in[14];
  const float* Wr    = (const float*)d_in[15];
  const float* Wk    = (const float*)d_in[16];
  const float* Wv    = (const float*)d_in[17];
  const float* Wg    = (const float*)d_in[18];
  const float* Wo    = (const float*)d_in[19];
  const float* gnw   = (const float*)d_in[20];
  const float* gnb   = (const float*)d_in[21];

  char* ws = (char*)d_ws;
  unsigned short* Wrt  = (unsigned short*)(ws + OFF_WRT);
  unsigned short* Wkt  = (unsigned short*)(ws + OFF_WKT);
  unsigned short* Wvt  = (unsigned short*)(ws + OFF_WVT);
  unsigned short* Wgt  = (unsigned short*)(ws + OFF_WGT);
  unsigned short* Wot  = (unsigned short*)(ws + OFF_WOT);
  unsigned short* w1t  = (unsigned short*)(ws + OFF_W1T);
  unsigned short* w2t  = (unsigned short*)(ws + OFF_W2T);
  unsigned short* td1t = (unsigned short*)(ws + OFF_TD1);
  unsigned short* td2t = (unsigned short*)(ws + OFF_TD2);
  unsigned short* t5   = (unsigned short*)(ws + OFF_T5);
  unsigned short* dtmp = (unsigned short*)(ws + OFF_DT);
  unsigned short* xg   = (unsigned short*)(ws + OFF_XG);
  unsigned short* obuf = (unsigned short*)(ws + OFF_XG);                        // after xg dead
  unsigned short* ybuf = (unsigned short*)(ws + OFF_XG) + (size_t)kM * kC;     // second half
  unsigned short* bufX = (unsigned short*)(ws + OFF_X);
  unsigned short* bufR = (unsigned short*)(ws + OFF_R);
  unsigned short* bufK = (unsigned short*)(ws + OFF_K);
  unsigned short* bufV = (unsigned short*)(ws + OFF_V);
  float*          Lbuf = (float*)(ws + OFF_L);
  float*          DsegP= (float*)(ws + OFF_TD1);

  float* outp  = (float*)d_out;
  float* lx    = outp + (size_t)kM * kC;
  float* stOut = lx + (size_t)kB * kC;

  dim3 blk(256);

  // weight prep
  trans_bf16<<<dim3(32, 32), blk, 0, stream>>>(Wr, Wrt, 2048, 2048);
  trans_bf16<<<dim3(32, 32), blk, 0, stream>>>(Wk, Wkt, 2048, 2048);
  trans_bf16<<<dim3(32, 32), blk, 0, stream>>>(Wv, Wvt, 2048, 2048);
  trans_bf16<<<dim3(32, 32), blk, 0, stream>>>(Wg, Wgt, 2048, 2048);
  trans_bf16<<<dim3(32, 32), blk, 0, stream>>>(Wo, Wot, 2048, 2048);
  trans_bf16<<<dim3(3, 32), blk, 0, stream>>>(w1, w1t, 2048, 160);
  trans_bf16<<<dim3(1, 32), blk, 0, stream>>>(tdw1, td1t, 2048, 64);
  trans_bf16<<<dim3(32, 1), blk, 0, stream>>>(tdw2, td2t, 64, 2048);
  trans_bf16<<<dim3(32, 3), blk, 0, stream>>>(w2, w2t, 160, 2048);

  // token shift + maa_x mix
  prep_x2<<<dim3(kM * kC / 4 / 256), blk, 0, stream>>>(x, shift, maax, bufX, lx);

  // t5 = tanh(xxx @ w1)
  gemm_k<128, 32, E_TANH><<<dim3(kM / 128, 5), blk, 0, stream>>>(bufX, w1t, t5, kM, 160, 2048);

  dim3 mgrid(kM / 64, kC / 64);
  constexpr int G256 = (kM / 256) * (kC / 256);
  constexpr size_t LDS256 = 131072;

  // fused 5-way mix: xw->X, xk->V, xv->R, xr->K, xg->XG  (reads x once)
  mix5f_k<<<mgrid, blk, 0, stream>>>(t5, w2t, x, shift, maaw, maak, maav, maar, maag,
                                     bufX, bufV, bufR, bufK, xg);
  // decay first stage: dtmp = tanh(xw @ tdw1)
  gemm_k<64, 64, E_TANH><<<dim3(kM / 64, 1), blk, 0, stream>>>(bufX, td1t, dtmp, kM, 64, 2048);

  // projections: k->X (xw dead), v->V (xk dead), r->R (xv dead), g->K (xr dead)
  gemm256_k<E_BF16><<<dim3(G256), dim3(512), LDS256, stream>>>(bufV, Wkt, bufX, kM, 2048, 2048);
  gemm256_k<E_BF16><<<dim3(G256), dim3(512), LDS256, stream>>>(bufR, Wvt, bufV, kM, 2048, 2048);
  gemm256_k<E_BF16><<<dim3(G256), dim3(512), LDS256, stream>>>(bufK, Wrt, bufR, kM, 2048, 2048);
  gemm256_k<E_SILU><<<dim3(G256), dim3(512), LDS256, stream>>>(xg, Wgt, bufK, kM, 2048, 2048);

  // WKV: pass1 (fused decay) -> combine -> pass2 (fused decay recompute; o -> obuf)
  wkv_local_k<<<dim3(kB * kH * SEGN), blk, 0, stream>>>(bufX, bufV, dtmp, td2t, tdec,
                                                        Lbuf, DsegP);
  wkv_combine_k<<<dim3(kB * kH), blk, 0, stream>>>(s0, DsegP, Lbuf, stOut);
  wkv_seg_k<<<dim3(kB * kH * SEGN), blk, 0, stream>>>(bufR, bufX, bufV, dtmp, td2t, tdec,
                                                      faaaa, Lbuf, obuf);

  // groupnorm * g -> y
  gn_k<<<dim3(kM * kH / 4), blk, 0, stream>>>(obuf, bufK, gnw, gnb, ybuf);

  // out = y @ Wo -> d_out
  gemm256_k<E_F32><<<dim3(G256), dim3(512), LDS256, stream>>>(ybuf, Wot, outp, kM, 2048, 2048);
}

// Round 21
// 1424.289 us; speedup vs baseline: 1.0082x; 1.0043x over previous
//
#include <hip/hip_runtime.h>
#include <hip/hip_bf16.h>
#include <stdint.h>

#define DEV __device__ __forceinline__

typedef __bf16 bf16x8 __attribute__((ext_vector_type(8)));
typedef float f32x4 __attribute__((ext_vector_type(4)));
typedef unsigned short u16x8 __attribute__((ext_vector_type(8)));

constexpr int kB = 4, kT = 4096, kC = 2048, kH = 32, kN = 64;
constexpr int kM = kB * kT; // 16384
constexpr int SEGN = 8, TSEG = kT / SEGN, CHN = TSEG / 64; // 8 segments x 512 t x 8 chunks

// ---------- bf16 helpers ----------
DEV float bfu2f(unsigned short u) {
  union { uint32_t i; float f; } x; x.i = ((uint32_t)u) << 16; return x.f;
}
DEV unsigned short f2bfu(float f) {
  union { float f; uint32_t i; } x; x.f = f;
  uint32_t r = x.i + 0x7FFFu + ((x.i >> 16) & 1u);
  return (unsigned short)(r >> 16);
}

DEV void gld16(const void* g, void* l) {
  __builtin_amdgcn_global_load_lds(
      (const __attribute__((address_space(1))) void*)g,
      (__attribute__((address_space(3))) void*)l, 16, 0, 0);
}

// swizzled byte offset within a [rows][128B] LDS tile (row-major, 64 bf16/row)
DEV int swzb(int row, int byteoff) { return (row << 7) + (byteoff ^ ((row & 7) << 4)); }

// ---------- generic transpose + fp32->bf16 ----------
__global__ __launch_bounds__(256) void trans_bf16(
    const float* __restrict__ in, unsigned short* __restrict__ out, int R, int Cn) {
  __shared__ __attribute__((aligned(16))) unsigned short tile[64][65];
  const int t = threadIdx.x;
  const int r0 = blockIdx.y * 64, c0 = blockIdx.x * 64;
  const int lr = t >> 6, lc = t & 63;
#pragma unroll
  for (int i = 0; i < 16; i++) {
    int rr = lr + i * 4;
    int gr = r0 + rr, gc = c0 + lc;
    if (gr < R && gc < Cn) tile[rr][lc] = f2bfu(in[(size_t)gr * Cn + gc]);
  }
  __syncthreads();
#pragma unroll
  for (int i = 0; i < 16; i++) {
    int cc = lr + i * 4;
    int gc = c0 + cc, gr = r0 + lc;
    if (gc < Cn && gr < R) out[(size_t)gc * R + gr] = tile[lc][cc];
  }
}

// ---------- prep: xxx = bf16(x + (shift(x)-x)*maa_x), lx copy ----------
__global__ __launch_bounds__(256) void prep_x2(
    const float* __restrict__ x, const float* __restrict__ shift,
    const float* __restrict__ maax,
    unsigned short* __restrict__ xxx, float* __restrict__ lx) {
  size_t i4 = ((size_t)blockIdx.x * 256 + threadIdx.x) * 4;
  int c = (int)(i4 & (kC - 1));
  size_t bt = i4 >> 11;
  int tt = (int)(bt & (kT - 1));
  int b = (int)(bt >> 12);
  float4 xv = *(const float4*)(x + i4);
  float4 pv = (tt == 0) ? *(const float4*)(shift + (size_t)b * kC + c)
                        : *(const float4*)(x + i4 - kC);
  float4 mx = *(const float4*)(maax + c);
  ushort4 o4;
  o4.x = f2bfu(xv.x + (pv.x - xv.x) * mx.x);
  o4.y = f2bfu(xv.y + (pv.y - xv.y) * mx.y);
  o4.z = f2bfu(xv.z + (pv.z - xv.z) * mx.z);
  o4.w = f2bfu(xv.w + (pv.w - xv.w) * mx.w);
  *(ushort4*)(xxx + i4) = o4;
  if (tt == kT - 1) *(float4*)(lx + (size_t)b * kC + c) = xv;
}

enum { E_F32 = 0, E_BF16 = 1, E_TANH = 2, E_SILU = 3 };

// ---------- small-shape bf16 MFMA GEMM (m97-style 128-tile) ----------
template <int BM, int BN, int EPI>
__global__ __launch_bounds__(256) void gemm_k(
    const unsigned short* __restrict__ A, const unsigned short* __restrict__ Bt,
    void* __restrict__ Cout, int M, int N, int K) {
  constexpr int WGM = (BM == 128 && BN == 128) ? 2 : (BM == 64 ? 2 : 4);
  constexpr int WGN = 4 / WGM;
  constexpr int WM = BM / WGM, WN = BN / WGN;
  constexpr int WR = WM / 16, WC = WN / 16;
  __shared__ __attribute__((aligned(16))) unsigned short As[BM * 32];
  __shared__ __attribute__((aligned(16))) unsigned short Bs[BN * 32];
  const int t = threadIdx.x, wid = t >> 6, l = t & 63;
  const int m0 = blockIdx.x * BM, n0 = blockIdx.y * BN;
  const int wm0 = (wid / WGN) * WM, wn0 = (wid % WGN) * WN;
  f32x4 acc[WR][WC];
#pragma unroll
  for (int i = 0; i < WR; i++)
#pragma unroll
    for (int j = 0; j < WC; j++) acc[i][j] = f32x4{0.f, 0.f, 0.f, 0.f};

  const int rowS = t >> 2, cbS = (t & 3) * 16;
  const char* Ab = (const char*)A;
  const char* Bb = (const char*)Bt;
  const int aoff = (wm0 + (l & 15)) * 32 + (l >> 4) * 8;
  const int boff = (wn0 + (l & 15)) * 32 + (l >> 4) * 8;

  for (int kt = 0; kt < K; kt += 32) {
#pragma unroll
    for (int ia = 0; ia < BM / 64; ia++)
      gld16(Ab + ((size_t)(m0 + ia * 64 + rowS) * K + kt) * 2 + cbS,
            (char*)As + ia * 4096 + wid * 1024);
    if constexpr (BN >= 64) {
#pragma unroll
      for (int ib = 0; ib < BN / 64; ib++)
        gld16(Bb + ((size_t)(n0 + ib * 64 + rowS) * K + kt) * 2 + cbS,
              (char*)Bs + ib * 4096 + wid * 1024);
    } else {
      if (t < BN * 4)
        gld16(Bb + ((size_t)(n0 + rowS) * K + kt) * 2 + cbS,
              (char*)Bs + wid * 1024);
    }
    __syncthreads();
    bf16x8 af[WR], bfv[WC];
#pragma unroll
    for (int mi = 0; mi < WR; mi++) af[mi] = *(const bf16x8*)(&As[aoff + mi * 512]);
#pragma unroll
    for (int ni = 0; ni < WC; ni++) bfv[ni] = *(const bf16x8*)(&Bs[boff + ni * 512]);
#pragma unroll
    for (int mi = 0; mi < WR; mi++)
#pragma unroll
      for (int ni = 0; ni < WC; ni++)
        acc[mi][ni] = __builtin_amdgcn_mfma_f32_16x16x32_bf16(af[mi], bfv[ni], acc[mi][ni], 0, 0, 0);
    __syncthreads();
  }

#pragma unroll
  for (int mi = 0; mi < WR; mi++) {
#pragma unroll
    for (int ni = 0; ni < WC; ni++) {
      int row = m0 + wm0 + mi * 16 + (l >> 4) * 4;
      int col = n0 + wn0 + ni * 16 + (l & 15);
#pragma unroll
      for (int j = 0; j < 4; j++) {
        float v = acc[mi][ni][j];
        size_t idx = (size_t)(row + j) * N + col;
        if constexpr (EPI == E_F32) ((float*)Cout)[idx] = v;
        else if constexpr (EPI == E_BF16) ((unsigned short*)Cout)[idx] = f2bfu(v);
        else if constexpr (EPI == E_TANH) ((unsigned short*)Cout)[idx] = f2bfu(tanhf(v));
        else if constexpr (EPI == E_SILU) ((unsigned short*)Cout)[idx] = f2bfu(v / (1.f + expf(-v)));
      }
    }
  }
}

// ---------- big GEMM: 256x256 tile, BK=64, 8 waves, m201-style 4-phase/K-tile ----------
#define GPH(PP, QQ, SKIND, KTB)                                                        \
  do {                                                                                 \
    const int aB_ = (PP) * 65536 + wr * 16384;                                         \
    const int bB_ = 32768 + (PP) * 65536 + bh * 16384;                                 \
    if ((QQ) == 0) {                                                                   \
      _Pragma("unroll")                                                                \
      for (int ni = 0; ni < 4; ni++) {                                                 \
        bfr[ni][0] = *(const bf16x8*)(lds + bB_ + bRow[ni] + bOffK0);                  \
        bfr[ni][1] = *(const bf16x8*)(lds + bB_ + bRow[ni] + bOffK1);                  \
      }                                                                                \
    }                                                                                  \
    bf16x8 a0k0_ = *(const bf16x8*)(lds + aB_ + (2 * (QQ)) * 2048 + aOffK0);           \
    bf16x8 a0k1_ = *(const bf16x8*)(lds + aB_ + (2 * (QQ)) * 2048 + aOffK1);           \
    bf16x8 a1k0_ = *(const bf16x8*)(lds + aB_ + (2 * (QQ) + 1) * 2048 + aOffK0);       \
    bf16x8 a1k1_ = *(const bf16x8*)(lds + aB_ + (2 * (QQ) + 1) * 2048 + aOffK1);       \
    if ((SKIND) == 1) {                                                                \
      const int d_ = ((PP) ^ 1) * 65536;                                               \
      gld16(pA0 + (KTB), lds + d_ + tid * 16);                                         \
      gld16(pA0 + (KTB) + (size_t)64 * kC * 2, lds + d_ + 8192 + tid * 16);            \
      gld16(pA1 + (KTB), lds + d_ + 16384 + tid * 16);                                 \
      gld16(pA1 + (KTB) + (size_t)64 * kC * 2, lds + d_ + 24576 + tid * 16);           \
    } else if ((SKIND) == 2) {                                                         \
      const int d_ = 32768 + (((PP) ^ 1) * 65536);                                     \
      gld16(pB0 + (KTB), lds + d_ + tid * 16);                                         \
      gld16(pB0 + (KTB) + (size_t)64 * kC * 2, lds + d_ + 8192 + tid * 16);            \
      gld16(pB1 + (KTB), lds + d_ + 16384 + tid * 16);                                 \
      gld16(pB1 + (KTB) + (size_t)64 * kC * 2, lds + d_ + 24576 + tid * 16);           \
    }                                                                                  \
    __builtin_amdgcn_s_barrier();                                                      \
    asm volatile("s_waitcnt lgkmcnt(0)" ::: "memory");                                 \
    __builtin_amdgcn_sched_barrier(0);                                                 \
    __builtin_amdgcn_s_setprio(1);                                                     \
    _Pragma("unroll")                                                                  \
    for (int ni = 0; ni < 4; ni++) {                                                   \
      acc[2 * (QQ)][ni] = __builtin_amdgcn_mfma_f32_16x16x32_bf16(a0k0_, bfr[ni][0], acc[2 * (QQ)][ni], 0, 0, 0);         \
      acc[2 * (QQ) + 1][ni] = __builtin_amdgcn_mfma_f32_16x16x32_bf16(a1k0_, bfr[ni][0], acc[2 * (QQ) + 1][ni], 0, 0, 0); \
      acc[2 * (QQ)][ni] = __builtin_amdgcn_mfma_f32_16x16x32_bf16(a0k1_, bfr[ni][1], acc[2 * (QQ)][ni], 0, 0, 0);         \
      acc[2 * (QQ) + 1][ni] = __builtin_amdgcn_mfma_f32_16x16x32_bf16(a1k1_, bfr[ni][1], acc[2 * (QQ) + 1][ni], 0, 0, 0); \
    }                                                                                  \
    __builtin_amdgcn_s_setprio(0);                                                     \
    if ((QQ) == 3) {                                                                   \
      asm volatile("s_waitcnt vmcnt(0)" ::: "memory");                                 \
      __builtin_amdgcn_sched_barrier(0);                                               \
    }                                                                                  \
    __builtin_amdgcn_s_barrier();                                                      \
    __builtin_amdgcn_sched_barrier(0);                                                 \
  } while (0)

template <int EPI>
__global__ __launch_bounds__(512, 1) void gemm256_k(
    const unsigned short* __restrict__ A, const unsigned short* __restrict__ Bt,
    void* __restrict__ Cout, int M, int N, int K) {
  extern __shared__ __attribute__((aligned(16))) char lds[];
  const int tid = threadIdx.x, wid = tid >> 6, l = tid & 63;
  const int fr = l & 15, fq = l >> 4;
  const int wr = wid >> 2, wc = wid & 3;
  const int bh = wc >> 1;

  const int mtiles = M >> 8, ntiles = N >> 8;
  const int slab = mtiles >> 3;
  const int xcd = blockIdx.x & 7, loc = blockIdx.x >> 3;
  const int m0 = (xcd * slab + loc / ntiles) * 256;
  const int n0 = (loc % ntiles) * 256;

  const int sr = tid >> 3;
  const int scb = ((tid & 7) * 16) ^ ((sr & 7) << 4);
  const char* pA0 = (const char*)A + (size_t)(m0 + sr) * K * 2 + scb;
  const char* pA1 = (const char*)A + (size_t)(m0 + 128 + sr) * K * 2 + scb;
  const char* pB0 = (const char*)Bt + (size_t)(n0 + sr) * K * 2 + scb;
  const char* pB1 = (const char*)Bt + (size_t)(n0 + 128 + sr) * K * 2 + scb;

  const int xorv = (fr & 7) << 4;
  const int aOffK0 = fr * 128 + ((fq * 16) ^ xorv);
  const int aOffK1 = fr * 128 + ((64 + fq * 16) ^ xorv);
  const int bOffK0 = aOffK0, bOffK1 = aOffK1;
  int bRow[4];
#pragma unroll
  for (int ni = 0; ni < 4; ni++) bRow[ni] = ((wc & 1) * 64 + ni * 16) * 128;

  f32x4 acc[8][4];
#pragma unroll
  for (int i = 0; i < 8; i++)
#pragma unroll
    for (int j = 0; j < 4; j++) acc[i][j] = f32x4{0.f, 0.f, 0.f, 0.f};
  bf16x8 bfr[4][2];

  const int KT = K >> 6;
  {
    gld16(pA0, lds + tid * 16);
    gld16(pA0 + (size_t)64 * kC * 2, lds + 8192 + tid * 16);
    gld16(pA1, lds + 16384 + tid * 16);
    gld16(pA1 + (size_t)64 * kC * 2, lds + 24576 + tid * 16);
    gld16(pB0, lds + 32768 + tid * 16);
    gld16(pB0 + (size_t)64 * kC * 2, lds + 32768 + 8192 + tid * 16);
    gld16(pB1, lds + 32768 + 16384 + tid * 16);
    gld16(pB1 + (size_t)64 * kC * 2, lds + 32768 + 24576 + tid * 16);
    asm volatile("s_waitcnt vmcnt(0)" ::: "memory");
    __builtin_amdgcn_s_barrier();
    __builtin_amdgcn_sched_barrier(0);
  }

  for (int T = 0; T < KT; ++T) {
    const int p = T & 1;
    const int st = (T + 1 < KT) ? 1 : 0;
    const int ktb = (T + 1) * 128;
    GPH(p, 0, st ? 1 : 0, ktb);
    GPH(p, 1, st ? 2 : 0, ktb);
    GPH(p, 2, 0, 0);
    GPH(p, 3, 0, 0);
  }

#pragma unroll
  for (int mi = 0; mi < 8; mi++)
#pragma unroll
    for (int ni = 0; ni < 4; ni++) {
      int row = m0 + wr * 128 + mi * 16 + fq * 4;
      int col = n0 + wc * 64 + ni * 16 + fr;
#pragma unroll
      for (int j = 0; j < 4; j++) {
        float v = acc[mi][ni][j];
        size_t idx = (size_t)(row + j) * N + col;
        if constexpr (EPI == E_F32) ((float*)Cout)[idx] = v;
        else if constexpr (EPI == E_BF16) ((unsigned short*)Cout)[idx] = f2bfu(v);
        else if constexpr (EPI == E_SILU) ((unsigned short*)Cout)[idx] = f2bfu(v / (1.f + expf(-v)));
      }
    }
}

// ---------- five-feature mix: direct-global fragments, sector-aligned stores ----------
// thread t owns row (t>>2); two 8-col chunks at (t&3)*8 and 32+(t&3)*8, so each
// u16x8 store across 4 consecutive lanes covers a contiguous 64B (full sectors).
__global__ __launch_bounds__(256) void mix5f_k(
    const unsigned short* __restrict__ t5, const unsigned short* __restrict__ w2t,
    const float* __restrict__ x, const float* __restrict__ shift,
    const float* __restrict__ maaw, const float* __restrict__ maak,
    const float* __restrict__ maav, const float* __restrict__ maar,
    const float* __restrict__ maag,
    unsigned short* __restrict__ xw, unsigned short* __restrict__ xk,
    unsigned short* __restrict__ xvo, unsigned short* __restrict__ xr,
    unsigned short* __restrict__ xg) {
  __shared__ __attribute__((aligned(16))) float tile[64][68];   // 17408B
  const int t = threadIdx.x, wid = t >> 6, l = t & 63;
  const int m0 = blockIdx.x * 64, n0 = blockIdx.y * 64;
  const int wm0 = (wid >> 1) * 32, wn0 = (wid & 1) * 32;
  const int fr = l & 15, fq = l >> 4;

  // direct-global fragment base pointers (16B-aligned, 16B contiguous per lane)
  const unsigned short* pa0 = t5 + (size_t)(m0 + wm0 + fr) * 160 + fq * 8;
  const unsigned short* pa1 = t5 + (size_t)(m0 + wm0 + 16 + fr) * 160 + fq * 8;
  const unsigned short* pb0 = w2t + (size_t)(n0 + wn0 + fr) * 160 + fq * 8;
  const unsigned short* pb1 = w2t + (size_t)(n0 + wn0 + 16 + fr) * 160 + fq * 8;

  // sector-aligned epilogue operands
  const int rrow = m0 + (t >> 2);
  const int ca = (t & 3) * 8;        // chunk A cols [ca, ca+8)
  const int cb = 32 + (t & 3) * 8;   // chunk B cols [cb, cb+8)
  const size_t baseA = (size_t)rrow * kC + n0 + ca;
  const size_t baseB = (size_t)rrow * kC + n0 + cb;
  float xA[8], dA[8], xB[8], dB[8];
  {
    const int tt = rrow & (kT - 1);
    const float* pvA = (tt == 0) ? (shift + (size_t)(rrow >> 12) * kC + n0 + ca)
                                 : (x + baseA - kC);
    const float* pvB = (tt == 0) ? (shift + (size_t)(rrow >> 12) * kC + n0 + cb)
                                 : (x + baseB - kC);
#pragma unroll
    for (int q = 0; q < 2; q++) {
      float4 xa = *(const float4*)(x + baseA + q * 4);
      float4 pa = *(const float4*)(pvA + q * 4);
      float4 xb = *(const float4*)(x + baseB + q * 4);
      float4 pb = *(const float4*)(pvB + q * 4);
      xA[q * 4 + 0] = xa.x; dA[q * 4 + 0] = pa.x - xa.x;
      xA[q * 4 + 1] = xa.y; dA[q * 4 + 1] = pa.y - xa.y;
      xA[q * 4 + 2] = xa.z; dA[q * 4 + 2] = pa.z - xa.z;
      xA[q * 4 + 3] = xa.w; dA[q * 4 + 3] = pa.w - xa.w;
      xB[q * 4 + 0] = xb.x; dB[q * 4 + 0] = pb.x - xb.x;
      xB[q * 4 + 1] = xb.y; dB[q * 4 + 1] = pb.y - xb.y;
      xB[q * 4 + 2] = xb.z; dB[q * 4 + 2] = pb.z - xb.z;
      xB[q * 4 + 3] = xb.w; dB[q * 4 + 3] = pb.w - xb.w;
    }
  }

  unsigned short* outs[5] = { xw, xk, xvo, xr, xg };
  const float* maas[5] = { maaw, maak, maav, maar, maag };
#pragma unroll
  for (int f = 0; f < 5; f++) {
    bf16x8 a0 = *(const bf16x8*)(pa0 + f * 32);
    bf16x8 a1 = *(const bf16x8*)(pa1 + f * 32);
    bf16x8 b0 = *(const bf16x8*)(pb0 + f * 32);
    bf16x8 b1 = *(const bf16x8*)(pb1 + f * 32);
    f32x4 ac00 = __builtin_amdgcn_mfma_f32_16x16x32_bf16(a0, b0, f32x4{0.f, 0.f, 0.f, 0.f}, 0, 0, 0);
    f32x4 ac01 = __builtin_amdgcn_mfma_f32_16x16x32_bf16(a0, b1, f32x4{0.f, 0.f, 0.f, 0.f}, 0, 0, 0);
    f32x4 ac10 = __builtin_amdgcn_mfma_f32_16x16x32_bf16(a1, b0, f32x4{0.f, 0.f, 0.f, 0.f}, 0, 0, 0);
    f32x4 ac11 = __builtin_amdgcn_mfma_f32_16x16x32_bf16(a1, b1, f32x4{0.f, 0.f, 0.f, 0.f}, 0, 0, 0);
    __syncthreads();   // prev feature's tile reads done (WAR)
#pragma unroll
    for (int j = 0; j < 4; j++) {
      tile[wm0 + fq * 4 + j][wn0 + fr]            = ac00[j];
      tile[wm0 + fq * 4 + j][wn0 + 16 + fr]       = ac01[j];
      tile[wm0 + 16 + fq * 4 + j][wn0 + fr]       = ac10[j];
      tile[wm0 + 16 + fq * 4 + j][wn0 + 16 + fr]  = ac11[j];
    }
    __syncthreads();   // tile ready
    const float* mpA = maas[f] + n0 + ca;
    const float* mpB = maas[f] + n0 + cb;
    u16x8 oA, oB;
#pragma unroll
    for (int q = 0; q < 2; q++) {
      f32x4 mA4 = *(const f32x4*)&tile[t >> 2][ca + q * 4];
      f32x4 mB4 = *(const f32x4*)&tile[t >> 2][cb + q * 4];
      float4 maA = *(const float4*)(mpA + q * 4);
      float4 maB = *(const float4*)(mpB + q * 4);
      float mvA[4] = { maA.x, maA.y, maA.z, maA.w };
      float mvB[4] = { maB.x, maB.y, maB.z, maB.w };
#pragma unroll
      for (int e = 0; e < 4; e++) {
        int i = q * 4 + e;
        oA[i] = f2bfu(xA[i] + dA[i] * (mvA[e] + mA4[e]));
        oB[i] = f2bfu(xB[i] + dB[i] * (mvB[e] + mB4[e]));
      }
    }
    *(u16x8*)(outs[f] + baseA) = oA;
    *(u16x8*)(outs[f] + baseB) = oB;
  }
}

// ---------- WKV pass 1: fused decay compute + local state (no edec materialization) ----------
__global__ __launch_bounds__(256) void wkv_local_k(
    const unsigned short* __restrict__ kb, const unsigned short* __restrict__ vb,
    const unsigned short* __restrict__ dtmp, const unsigned short* __restrict__ td2t,
    const float* __restrict__ tdec,
    float* __restrict__ Lbuf, float* __restrict__ Dseg) {
  const int bid = blockIdx.x;
  const int bh = bid >> 3, seg = bid & 7;
  const int h = bh & 31, b = bh >> 5;
  const int tid = threadIdx.x, w = tid >> 6, l = tid & 63;
  __shared__ __attribute__((aligned(16))) char arena[32768];
  char* KQks = arena;
  char* Vt   = arena + 8192;
  float* EdB = (float*)arena;
  char* TdB  = arena + 16384;
  char* DtA  = arena + 24576;
  __shared__ float segp[4][64];
  __shared__ float DLs[64];
  __shared__ float tdf[64];

  const int fr = l & 15, fq = l >> 4;
  f32x4 Sreg[4];
#pragma unroll
  for (int ni = 0; ni < 4; ni++) Sreg[ni] = f32x4{0.f, 0.f, 0.f, 0.f};

  {
    int r1 = tid >> 3, r2 = 32 + r1;
    int cb1 = ((tid & 7) * 16) ^ ((r1 & 7) << 4);
    int cb2 = ((tid & 7) * 16) ^ ((r2 & 7) << 4);
    gld16((const char*)td2t + (size_t)(h * 64 + r1) * 128 + cb1, TdB + w * 1024);
    gld16((const char*)td2t + (size_t)(h * 64 + r2) * 128 + cb2, TdB + 4096 + w * 1024);
    if (tid < 64) tdf[tid] = tdec[h * 64 + tid];
  }

  float dtot = 1.f;
  float kv[16], vv[16];
  {
    size_t g = ((size_t)b * kT + seg * TSEG + w * 16) * kC + h * 64 + l;
#pragma unroll
    for (int i = 0; i < 16; i++) {
      kv[i] = bfu2f(kb[g]); vv[i] = bfu2f(vb[g]);
      g += kC;
    }
  }

  for (int ch = 0; ch < CHN; ++ch) {
    const size_t gt0 = (size_t)b * kT + seg * TSEG + ch * 64;
    {
      int r1 = tid >> 3, r2 = 32 + r1;
      int cb1 = ((tid & 7) * 16) ^ ((r1 & 7) << 4);
      int cb2 = ((tid & 7) * 16) ^ ((r2 & 7) << 4);
      gld16((const char*)dtmp + (gt0 + r1) * 128 + cb1, DtA + w * 1024);
      gld16((const char*)dtmp + (gt0 + r2) * 128 + cb2, DtA + 4096 + w * 1024);
    }
    __syncthreads();  // B0

    f32x4 dacc[4];
    {
      bf16x8 af0 = *(const bf16x8*)(DtA + swzb(w * 16 + fr, fq * 16));
      bf16x8 af1 = *(const bf16x8*)(DtA + swzb(w * 16 + fr, fq * 16 + 64));
#pragma unroll
      for (int nj = 0; nj < 4; nj++) {
        bf16x8 b0 = *(const bf16x8*)(TdB + swzb(nj * 16 + fr, fq * 16));
        bf16x8 b1 = *(const bf16x8*)(TdB + swzb(nj * 16 + fr, fq * 16 + 64));
        dacc[nj] = __builtin_amdgcn_mfma_f32_16x16x32_bf16(af0, b0, f32x4{0.f, 0.f, 0.f, 0.f}, 0, 0, 0);
        dacc[nj] = __builtin_amdgcn_mfma_f32_16x16x32_bf16(af1, b1, dacc[nj], 0, 0, 0);
      }
    }
#pragma unroll
    for (int nj = 0; nj < 4; nj++) {
      float tv = tdf[nj * 16 + fr];
#pragma unroll
      for (int j = 0; j < 4; j++)
        EdB[(w * 16 + fq * 4 + j) * 64 + nj * 16 + fr] = expf(-expf(dacc[nj][j] + tv));
    }
    float dvv[16];
    float p = 1.f;
#pragma unroll
    for (int i = 0; i < 16; i++) {
      float d = EdB[(w * 16 + i) * 64 + l];
      dvv[i] = d; p *= d;
    }
    segp[w][l] = p;
    __syncthreads();  // B2

    float pre = 1.f;
    if (w > 0) pre *= segp[0][l];
    if (w > 1) pre *= segp[1][l];
    if (w > 2) pre *= segp[2][l];
    if (w == 3) DLs[l] = pre * p;

    unsigned short kqrow[16], vtrow[16];
    float run = pre;
#pragma unroll
    for (int i = 0; i < 16; i++) {
      run *= dvv[i];
      kqrow[i] = f2bfu(kv[i] / run);
      vtrow[i] = f2bfu(vv[i]);
    }
    {
      u16x8 q0, q1, v0, v1;
#pragma unroll
      for (int j = 0; j < 8; j++) { q0[j] = kqrow[j]; q1[j] = kqrow[j + 8]; v0[j] = vtrow[j]; v1[j] = vtrow[j + 8]; }
      *(u16x8*)(KQks + swzb(l, w * 32)) = q0;
      *(u16x8*)(KQks + swzb(l, w * 32 + 16)) = q1;
      *(u16x8*)(Vt + swzb(l, w * 32)) = v0;
      *(u16x8*)(Vt + swzb(l, w * 32 + 16)) = v1;
    }
    if (ch < CHN - 1) {
      size_t g = ((size_t)b * kT + seg * TSEG + (ch + 1) * 64 + w * 16) * kC + h * 64 + l;
#pragma unroll
      for (int i = 0; i < 16; i++) {
        kv[i] = bfu2f(kb[g]); vv[i] = bfu2f(vb[g]);
        g += kC;
      }
    }
    __syncthreads();  // B3

    bf16x8 kA0 = *(const bf16x8*)(KQks + swzb(w * 16 + fr, fq * 16));
    bf16x8 kA1 = *(const bf16x8*)(KQks + swzb(w * 16 + fr, fq * 16 + 64));
    f32x4 kvacc[4];
#pragma unroll
    for (int ni = 0; ni < 4; ni++) {
      bf16x8 bv0 = *(const bf16x8*)(Vt + swzb(ni * 16 + fr, fq * 16));
      bf16x8 bv1 = *(const bf16x8*)(Vt + swzb(ni * 16 + fr, fq * 16 + 64));
      kvacc[ni] = __builtin_amdgcn_mfma_f32_16x16x32_bf16(kA0, bv0, f32x4{0.f, 0.f, 0.f, 0.f}, 0, 0, 0);
      kvacc[ni] = __builtin_amdgcn_mfma_f32_16x16x32_bf16(kA1, bv1, kvacc[ni], 0, 0, 0);
    }
    float dlj[4];
#pragma unroll
    for (int j = 0; j < 4; j++) dlj[j] = DLs[w * 16 + fq * 4 + j];
#pragma unroll
    for (int ni = 0; ni < 4; ni++)
#pragma unroll
      for (int j = 0; j < 4; j++)
        Sreg[ni][j] = (Sreg[ni][j] + kvacc[ni][j]) * dlj[j];
    dtot *= DLs[l];
  }

  float* Lp = Lbuf + (size_t)bid * 4096;
#pragma unroll
  for (int ni = 0; ni < 4; ni++)
#pragma unroll
    for (int j = 0; j < 4; j++)
      Lp[(size_t)(w * 16 + fq * 4 + j) * 64 + ni * 16 + fr] = Sreg[ni][j];
  if (w == 0) Dseg[(size_t)bid * 64 + l] = dtot;
}

// ---------- WKV combine ----------
__global__ __launch_bounds__(256) void wkv_combine_k(
    const float* __restrict__ s0, const float* __restrict__ Dseg,
    float* __restrict__ Lbuf, float* __restrict__ sOut) {
  const int bh = blockIdx.x, tid = threadIdx.x;
  const int k = tid >> 2, v0 = (tid & 3) * 16;
  float4 s[4];
  const float* sp = s0 + (size_t)bh * 4096 + (size_t)k * 64 + v0;
#pragma unroll
  for (int q = 0; q < 4; q++) s[q] = ((const float4*)sp)[q];
  for (int seg = 0; seg < SEGN; ++seg) {
    size_t idx = (size_t)bh * SEGN + seg;
    float d = Dseg[idx * 64 + k];
    float* Lp = Lbuf + idx * 4096 + (size_t)k * 64 + v0;
#pragma unroll
    for (int q = 0; q < 4; q++) {
      float4 lq = ((float4*)Lp)[q];
      ((float4*)Lp)[q] = s[q];
      s[q].x = d * s[q].x + lq.x; s[q].y = d * s[q].y + lq.y;
      s[q].z = d * s[q].z + lq.z; s[q].w = d * s[q].w + lq.w;
    }
  }
  float* op = sOut + (size_t)bh * 4096 + (size_t)k * 64 + v0;
#pragma unroll
  for (int q = 0; q < 4; q++) ((float4*)op)[q] = s[q];
}

// ---------- WKV pass 2: fused decay recompute (no edec read), o -> HBM ----------
__global__ __launch_bounds__(256) void wkv_seg_k(
    const unsigned short* __restrict__ rb, const unsigned short* __restrict__ kb,
    const unsigned short* __restrict__ vb,
    const unsigned short* __restrict__ dtmp, const unsigned short* __restrict__ td2t,
    const float* __restrict__ tdec,
    const float* __restrict__ uf, const float* __restrict__ Sini,
    unsigned short* __restrict__ o) {
  const int bid = blockIdx.x;
  const int bh = bid >> 3, seg = bid & 7;
  const int h = bh & 31, b = bh >> 5;
  const int tid = threadIdx.x, w = tid >> 6, l = tid & 63;
  __shared__ __attribute__((aligned(16))) char arena[65536];
  char* RQ   = arena;
  char* KQsk = arena + 8192;
  char* KQks = arena + 16384;
  char* Vt   = arena + 24576;
  char* Pl   = arena + 32768;
  char* S0T  = arena + 40960;
  char* RU   = arena + 49152;
  char* Ksk  = arena + 57344;
  float* EdB = (float*)arena;
  char* DtA  = RU;
  char* TdB  = Ksk;
  __shared__ float segp[4][64];
  __shared__ float DLs[64];
  __shared__ float tdf[64];

  const float uu = uf[h * 64 + l];
  const int fr = l & 15, fq = l >> 4;
  if (tid < 64) tdf[tid] = tdec[h * 64 + tid];

  f32x4 Sreg[4];
#pragma unroll
  for (int ni = 0; ni < 4; ni++)
#pragma unroll
    for (int j = 0; j < 4; j++) {
      int kk2 = w * 16 + fq * 4 + j, vv2 = ni * 16 + fr;
      float sv = Sini[(size_t)bid * 4096 + (size_t)kk2 * 64 + vv2];
      Sreg[ni][j] = sv;
      *(unsigned short*)(S0T + swzb(vv2, kk2 * 2)) = f2bfu(sv);
    }
  __syncthreads();

  float rv[16], kv[16], vv[16];
  {
    size_t g = ((size_t)b * kT + seg * TSEG + w * 16) * kC + h * 64 + l;
#pragma unroll
    for (int i = 0; i < 16; i++) {
      rv[i] = bfu2f(rb[g]); kv[i] = bfu2f(kb[g]); vv[i] = bfu2f(vb[g]);
      g += kC;
    }
  }

  const int r1s = tid >> 3, r2s = 32 + r1s;
  const int cb1 = ((tid & 7) * 16) ^ ((r1s & 7) << 4);
  const int cb2 = ((tid & 7) * 16) ^ ((r2s & 7) << 4);

  for (int ch = 0; ch < CHN; ++ch) {
    const size_t gt0 = (size_t)b * kT + seg * TSEG + ch * 64;
    gld16((const char*)dtmp + (gt0 + r1s) * 128 + cb1, DtA + w * 1024);
    gld16((const char*)dtmp + (gt0 + r2s) * 128 + cb2, DtA + 4096 + w * 1024);
    gld16((const char*)td2t + (size_t)(h * 64 + r1s) * 128 + cb1, TdB + w * 1024);
    gld16((const char*)td2t + (size_t)(h * 64 + r2s) * 128 + cb2, TdB + 4096 + w * 1024);
    __syncthreads();   // S1

    f32x4 dacc[4];
    {
      bf16x8 af0 = *(const bf16x8*)(DtA + swzb(w * 16 + fr, fq * 16));
      bf16x8 af1 = *(const bf16x8*)(DtA + swzb(w * 16 + fr, fq * 16 + 64));
#pragma unroll
      for (int nj = 0; nj < 4; nj++) {
        bf16x8 b0 = *(const bf16x8*)(TdB + swzb(nj * 16 + fr, fq * 16));
        bf16x8 b1 = *(const bf16x8*)(TdB + swzb(nj * 16 + fr, fq * 16 + 64));
        dacc[nj] = __builtin_amdgcn_mfma_f32_16x16x32_bf16(af0, b0, f32x4{0.f, 0.f, 0.f, 0.f}, 0, 0, 0);
        dacc[nj] = __builtin_amdgcn_mfma_f32_16x16x32_bf16(af1, b1, dacc[nj], 0, 0, 0);
      }
    }
#pragma unroll
    for (int nj = 0; nj < 4; nj++) {
      float tv = tdf[nj * 16 + fr];
#pragma unroll
      for (int j = 0; j < 4; j++)
        EdB[(w * 16 + fq * 4 + j) * 64 + nj * 16 + fr] = expf(-expf(dacc[nj][j] + tv));
    }
    float dv[16];
    float p = 1.f;
#pragma unroll
    for (int i = 0; i < 16; i++) {
      dv[i] = EdB[(w * 16 + i) * 64 + l];
      p *= dv[i];
    }
    segp[w][l] = p;
    __syncthreads();   // S2

    float pre = 1.f;
    if (w > 0) pre *= segp[0][l];
    if (w > 1) pre *= segp[1][l];
    if (w > 2) pre *= segp[2][l];
    if (w == 3) DLs[l] = pre * p;

    unsigned short kqrow[16], vtrow[16];
    float run = pre;
#pragma unroll
    for (int i = 0; i < 16; i++) {
      int t = w * 16 + i;
      float rq = rv[i] * run;
      run *= dv[i];
      float kq = kv[i] / run;
      *(unsigned short*)(RQ + swzb(t, l * 2)) = f2bfu(rq);
      *(unsigned short*)(RU + swzb(t, l * 2)) = f2bfu(rv[i] * uu);
      *(unsigned short*)(Ksk + swzb(t, l * 2)) = f2bfu(kv[i]);
      unsigned short kqu = f2bfu(kq);
      *(unsigned short*)(KQsk + swzb(t, l * 2)) = kqu;
      kqrow[i] = kqu;
      vtrow[i] = f2bfu(vv[i]);
    }
    {
      u16x8 q0, q1, v0, v1;
#pragma unroll
      for (int j = 0; j < 8; j++) { q0[j] = kqrow[j]; q1[j] = kqrow[j + 8]; v0[j] = vtrow[j]; v1[j] = vtrow[j + 8]; }
      *(u16x8*)(KQks + swzb(l, w * 32)) = q0;
      *(u16x8*)(KQks + swzb(l, w * 32 + 16)) = q1;
      *(u16x8*)(Vt + swzb(l, w * 32)) = v0;
      *(u16x8*)(Vt + swzb(l, w * 32 + 16)) = v1;
    }

    if (ch < CHN - 1) {
      size_t g = ((size_t)b * kT + seg * TSEG + (ch + 1) * 64 + w * 16) * kC + h * 64 + l;
#pragma unroll
      for (int i = 0; i < 16; i++) {
        rv[i] = bfu2f(rb[g]); kv[i] = bfu2f(kb[g]); vv[i] = bfu2f(vb[g]);
        g += kC;
      }
    }
    __syncthreads();   // S3

    bf16x8 a0 = *(const bf16x8*)(RQ + swzb(w * 16 + fr, fq * 16));
    bf16x8 a1 = *(const bf16x8*)(RQ + swzb(w * 16 + fr, fq * 16 + 64));
    f32x4 pacc[4];
#pragma unroll
    for (int ni = 0; ni < 4; ni++) {
      bf16x8 b0 = *(const bf16x8*)(KQsk + swzb(ni * 16 + fr, fq * 16));
      bf16x8 b1 = *(const bf16x8*)(KQsk + swzb(ni * 16 + fr, fq * 16 + 64));
      pacc[ni] = __builtin_amdgcn_mfma_f32_16x16x32_bf16(a0, b0, f32x4{0.f, 0.f, 0.f, 0.f}, 0, 0, 0);
      pacc[ni] = __builtin_amdgcn_mfma_f32_16x16x32_bf16(a1, b1, pacc[ni], 0, 0, 0);
    }
    f32x4 dacc2;
    {
      bf16x8 ru0 = *(const bf16x8*)(RU + swzb(w * 16 + fr, fq * 16));
      bf16x8 ru1 = *(const bf16x8*)(RU + swzb(w * 16 + fr, fq * 16 + 64));
      bf16x8 kb0 = *(const bf16x8*)(Ksk + swzb(w * 16 + fr, fq * 16));
      bf16x8 kb1 = *(const bf16x8*)(Ksk + swzb(w * 16 + fr, fq * 16 + 64));
      dacc2 = __builtin_amdgcn_mfma_f32_16x16x32_bf16(ru0, kb0, f32x4{0.f, 0.f, 0.f, 0.f}, 0, 0, 0);
      dacc2 = __builtin_amdgcn_mfma_f32_16x16x32_bf16(ru1, kb1, dacc2, 0, 0, 0);
    }
    float dg[4];
#pragma unroll
    for (int j = 0; j < 4; j++) dg[j] = __shfl(dacc2[j], fq * 20 + j, 64);
#pragma unroll
    for (int ni = 0; ni < 4; ni++)
#pragma unroll
      for (int j = 0; j < 4; j++) {
        int row = w * 16 + fq * 4 + j, col = ni * 16 + fr;
        float pv = pacc[ni][j];
        pv = (col < row) ? pv : ((col == row) ? dg[j] : 0.f);
        *(unsigned short*)(Pl + swzb(row, col * 2)) = f2bfu(pv);
      }
    __syncthreads();   // S4

    bf16x8 pA0 = *(const bf16x8*)(Pl + swzb(w * 16 + fr, fq * 16));
    bf16x8 pA1 = *(const bf16x8*)(Pl + swzb(w * 16 + fr, fq * 16 + 64));
    bf16x8 kA0 = *(const bf16x8*)(KQks + swzb(w * 16 + fr, fq * 16));
    bf16x8 kA1 = *(const bf16x8*)(KQks + swzb(w * 16 + fr, fq * 16 + 64));
    f32x4 oacc[4], kvacc[4];
#pragma unroll
    for (int ni = 0; ni < 4; ni++) {
      bf16x8 bv0 = *(const bf16x8*)(Vt + swzb(ni * 16 + fr, fq * 16));
      bf16x8 bv1 = *(const bf16x8*)(Vt + swzb(ni * 16 + fr, fq * 16 + 64));
      bf16x8 bs0 = *(const bf16x8*)(S0T + swzb(ni * 16 + fr, fq * 16));
      bf16x8 bs1 = *(const bf16x8*)(S0T + swzb(ni * 16 + fr, fq * 16 + 64));
      oacc[ni] = __builtin_amdgcn_mfma_f32_16x16x32_bf16(pA0, bv0, f32x4{0.f, 0.f, 0.f, 0.f}, 0, 0, 0);
      oacc[ni] = __builtin_amdgcn_mfma_f32_16x16x32_bf16(pA1, bv1, oacc[ni], 0, 0, 0);
      oacc[ni] = __builtin_amdgcn_mfma_f32_16x16x32_bf16(a0, bs0, oacc[ni], 0, 0, 0);
      oacc[ni] = __builtin_amdgcn_mfma_f32_16x16x32_bf16(a1, bs1, oacc[ni], 0, 0, 0);
      kvacc[ni] = __builtin_amdgcn_mfma_f32_16x16x32_bf16(kA0, bv0, f32x4{0.f, 0.f, 0.f, 0.f}, 0, 0, 0);
      kvacc[ni] = __builtin_amdgcn_mfma_f32_16x16x32_bf16(kA1, bv1, kvacc[ni], 0, 0, 0);
    }
    size_t obase = gt0 * kC + h * 64;
#pragma unroll
    for (int ni = 0; ni < 4; ni++)
#pragma unroll
      for (int j = 0; j < 4; j++)
        o[obase + (size_t)(w * 16 + fq * 4 + j) * kC + ni * 16 + fr] = f2bfu(oacc[ni][j]);
    __syncthreads();   // S5

    float dlj[4];
#pragma unroll
    for (int j = 0; j < 4; j++) dlj[j] = DLs[w * 16 + fq * 4 + j];
#pragma unroll
    for (int ni = 0; ni < 4; ni++)
#pragma unroll
      for (int j = 0; j < 4; j++) {
        int kk2 = w * 16 + fq * 4 + j, vv2 = ni * 16 + fr;
        float sn = (Sreg[ni][j] + kvacc[ni][j]) * dlj[j];
        Sreg[ni][j] = sn;
        *(unsigned short*)(S0T + swzb(vv2, kk2 * 2)) = f2bfu(sn);
      }
  }
}

// ---------- GroupNorm over N=64 per (b,t,h), times g, -> bf16 ----------
__global__ __launch_bounds__(256) void gn_k(
    const unsigned short* __restrict__ o, const unsigned short* __restrict__ gb,
    const float* __restrict__ gnw, const float* __restrict__ gnb,
    unsigned short* __restrict__ y) {
  int gi = blockIdx.x * 4 + (threadIdx.x >> 6);
  int j = threadIdx.x & 63;
  int bt = gi >> 5, h = gi & 31;
  size_t idx = (size_t)bt * kC + h * 64 + j;
  float val = bfu2f(o[idx]);
  float s = val, s2 = val * val;
#pragma unroll
  for (int m = 1; m < 64; m <<= 1) {
    s += __shfl_xor(s, m, 64);
    s2 += __shfl_xor(s2, m, 64);
  }
  float mu = s * 0.015625f;
  float var = s2 * 0.015625f - mu * mu;
  float rs = rsqrtf(var + 6.4e-4f);
  float on = (val - mu) * rs * gnw[h * 64 + j] + gnb[h * 64 + j];
  y[idx] = f2bfu(on * bfu2f(gb[idx]));
}

// ---------- workspace layout ----------
constexpr size_t SZW     = (size_t)2048 * 2048 * 2;
constexpr size_t OFF_WRT = 0;
constexpr size_t OFF_WKT = 1 * SZW;
constexpr size_t OFF_WVT = 2 * SZW;
constexpr size_t OFF_WGT = 3 * SZW;
constexpr size_t OFF_WOT = 4 * SZW;
constexpr size_t OFF_W1T = 5 * SZW;
constexpr size_t OFF_W2T = OFF_W1T + (size_t)160 * 2048 * 2;
constexpr size_t OFF_TD1 = OFF_W2T + (size_t)2048 * 160 * 2;     // later Dseg f32
constexpr size_t OFF_TD2 = OFF_TD1 + (size_t)64 * 2048 * 2;
constexpr size_t OFF_T5  = OFF_TD2 + (size_t)2048 * 64 * 2;
constexpr size_t OFF_DT  = OFF_T5 + (size_t)kM * 160 * 2;
constexpr size_t OFF_XG  = OFF_DT + (size_t)kM * 64 * 2;         // xg bf16; later o bf16 + y bf16
constexpr size_t OFF_X   = OFF_XG + (size_t)kM * kC * 4;         // xxx/xw; k
constexpr size_t OFF_R   = OFF_X + (size_t)kM * kC * 2;          // xv; r
constexpr size_t OFF_K   = OFF_R + (size_t)kM * kC * 2;          // xr; g
constexpr size_t OFF_V   = OFF_K + (size_t)kM * kC * 2;          // xk; v
constexpr size_t OFF_L   = OFF_WRT;

extern "C" void kernel_launch(void* const* d_in, const int* in_sizes, int n_in,
                              void* d_out, int out_size, void* d_ws, size_t ws_size,
                              hipStream_t stream) {
  const float* x     = (const float*)d_in[0];
  const float* shift = (const float*)d_in[1];
  const float* s0    = (const float*)d_in[2];
  const float* maax  = (const float*)d_in[3];
  const float* maaw  = (const float*)d_in[4];
  const float* maak  = (const float*)d_in[5];
  const float* maav  = (const float*)d_in[6];
  const float* maar  = (const float*)d_in[7];
  const float* maag  = (const float*)d_in[8];
  const float* w1    = (const float*)d_in[9];
  const float* w2    = (const float*)d_in[10];
  const float* tdec  = (const float*)d_in[11];
  const float* tdw1  = (const float*)d_in[12];
  const float* tdw2  = (const float*)d_in[13];
  const float* faaaa = (const float*)d_in[14];
  const float* Wr    = (const float*)d_in[15];
  const float* Wk    = (const float*)d_in[16];
  const float* Wv    = (const float*)d_in[17];
  const float* Wg    = (const float*)d_in[18];
  const float* Wo    = (const float*)d_in[19];
  const float* gnw   = (const float*)d_in[20];
  const float* gnb   = (const float*)d_in[21];

  char* ws = (char*)d_ws;
  unsigned short* Wrt  = (unsigned short*)(ws + OFF_WRT);
  unsigned short* Wkt  = (unsigned short*)(ws + OFF_WKT);
  unsigned short* Wvt  = (unsigned short*)(ws + OFF_WVT);
  unsigned short* Wgt  = (unsigned short*)(ws + OFF_WGT);
  unsigned short* Wot  = (unsigned short*)(ws + OFF_WOT);
  unsigned short* w1t  = (unsigned short*)(ws + OFF_W1T);
  unsigned short* w2t  = (unsigned short*)(ws + OFF_W2T);
  unsigned short* td1t = (unsigned short*)(ws + OFF_TD1);
  unsigned short* td2t = (unsigned short*)(ws + OFF_TD2);
  unsigned short* t5   = (unsigned short*)(ws + OFF_T5);
  unsigned short* dtmp = (unsigned short*)(ws + OFF_DT);
  unsigned short* xg   = (unsigned short*)(ws + OFF_XG);
  unsigned short* obuf = (unsigned short*)(ws + OFF_XG);                        // after xg dead
  unsigned short* ybuf = (unsigned short*)(ws + OFF_XG) + (size_t)kM * kC;     // second half
  unsigned short* bufX = (unsigned short*)(ws + OFF_X);
  unsigned short* bufR = (unsigned short*)(ws + OFF_R);
  unsigned short* bufK = (unsigned short*)(ws + OFF_K);
  unsigned short* bufV = (unsigned short*)(ws + OFF_V);
  float*          Lbuf = (float*)(ws + OFF_L);
  float*          DsegP= (float*)(ws + OFF_TD1);

  float* outp  = (float*)d_out;
  float* lx    = outp + (size_t)kM * kC;
  float* stOut = lx + (size_t)kB * kC;

  dim3 blk(256);

  // weight prep
  trans_bf16<<<dim3(32, 32), blk, 0, stream>>>(Wr, Wrt, 2048, 2048);
  trans_bf16<<<dim3(32, 32), blk, 0, stream>>>(Wk, Wkt, 2048, 2048);
  trans_bf16<<<dim3(32, 32), blk, 0, stream>>>(Wv, Wvt, 2048, 2048);
  trans_bf16<<<dim3(32, 32), blk, 0, stream>>>(Wg, Wgt, 2048, 2048);
  trans_bf16<<<dim3(32, 32), blk, 0, stream>>>(Wo, Wot, 2048, 2048);
  trans_bf16<<<dim3(3, 32), blk, 0, stream>>>(w1, w1t, 2048, 160);
  trans_bf16<<<dim3(1, 32), blk, 0, stream>>>(tdw1, td1t, 2048, 64);
  trans_bf16<<<dim3(32, 1), blk, 0, stream>>>(tdw2, td2t, 64, 2048);
  trans_bf16<<<dim3(32, 3), blk, 0, stream>>>(w2, w2t, 160, 2048);

  // token shift + maa_x mix
  prep_x2<<<dim3(kM * kC / 4 / 256), blk, 0, stream>>>(x, shift, maax, bufX, lx);

  // t5 = tanh(xxx @ w1)
  gemm_k<128, 32, E_TANH><<<dim3(kM / 128, 5), blk, 0, stream>>>(bufX, w1t, t5, kM, 160, 2048);

  dim3 mgrid(kM / 64, kC / 64);
  constexpr int G256 = (kM / 256) * (kC / 256);
  constexpr size_t LDS256 = 131072;

  // fused 5-way mix: xw->X, xk->V, xv->R, xr->K, xg->XG  (reads x once)
  mix5f_k<<<mgrid, blk, 0, stream>>>(t5, w2t, x, shift, maaw, maak, maav, maar, maag,
                                     bufX, bufV, bufR, bufK, xg);
  // decay first stage: dtmp = tanh(xw @ tdw1)
  gemm_k<64, 64, E_TANH><<<dim3(kM / 64, 1), blk, 0, stream>>>(bufX, td1t, dtmp, kM, 64, 2048);

  // projections: k->X (xw dead), v->V (xk dead), r->R (xv dead), g->K (xr dead)
  gemm256_k<E_BF16><<<dim3(G256), dim3(512), LDS256, stream>>>(bufV, Wkt, bufX, kM, 2048, 2048);
  gemm256_k<E_BF16><<<dim3(G256), dim3(512), LDS256, stream>>>(bufR, Wvt, bufV, kM, 2048, 2048);
  gemm256_k<E_BF16><<<dim3(G256), dim3(512), LDS256, stream>>>(bufK, Wrt, bufR, kM, 2048, 2048);
  gemm256_k<E_SILU><<<dim3(G256), dim3(512), LDS256, stream>>>(xg, Wgt, bufK, kM, 2048, 2048);

  // WKV: pass1 (fused decay) -> combine -> pass2 (fused decay recompute; o -> obuf)
  wkv_local_k<<<dim3(kB * kH * SEGN), blk, 0, stream>>>(bufX, bufV, dtmp, td2t, tdec,
                                                        Lbuf, DsegP);
  wkv_combine_k<<<dim3(kB * kH), blk, 0, stream>>>(s0, DsegP, Lbuf, stOut);
  wkv_seg_k<<<dim3(kB * kH * SEGN), blk, 0, stream>>>(bufR, bufX, bufV, dtmp, td2t, tdec,
                                                      faaaa, Lbuf, obuf);

  // groupnorm * g -> y
  gn_k<<<dim3(kM * kH / 4), blk, 0, stream>>>(obuf, bufK, gnw, gnb, ybuf);

  // out = y @ Wo -> d_out
  gemm256_k<E_F32><<<dim3(G256), dim3(512), LDS256, stream>>>(ybuf, Wot, outp, kM, 2048, 2048);
}